// Round 6
// baseline (1212.964 us; speedup 1.0000x reference)
//
#include <hip/hip_runtime.h>
#include <hip/hip_bf16.h>
#include <math.h>

#define NG 128
#define CHUNK 4096

typedef __attribute__((ext_vector_type(8))) short short8;
typedef __attribute__((ext_vector_type(4))) float float4v;

static __device__ __forceinline__ float bf2f(__hip_bfloat16 v) { return __bfloat162float(v); }

// ---------- per-node in-degree + dinv ----------
__global__ void k_hist(const int* __restrict__ dst, int* __restrict__ counts, int e) {
    int i = blockIdx.x * blockDim.x + threadIdx.x;
    if (i < e) atomicAdd(&counts[dst[i]], 1);
}

__global__ void k_dinv_ew(const int* __restrict__ counts, float* __restrict__ dinv, int n) {
    int i = blockIdx.x * blockDim.x + threadIdx.x;
    if (i < n) dinv[i] = rsqrtf((float)counts[i] + 1.0f);  // +1 self-loop
}

// ---------- generic exclusive scan (512-thread blocks) ----------
__global__ void __launch_bounds__(512) genscan1(int* __restrict__ a, int* __restrict__ bsums, int n) {
    __shared__ int s[512];
    int tid = threadIdx.x;
    int i = blockIdx.x * 512 + tid;
    int v = (i < n) ? a[i] : 0;
    s[tid] = v;
    __syncthreads();
    for (int d = 1; d < 512; d <<= 1) {
        int t = (tid >= d) ? s[tid - d] : 0;
        __syncthreads();
        s[tid] += t;
        __syncthreads();
    }
    if (i < n) a[i] = s[tid] - v;   // exclusive, in place
    if (tid == 511) bsums[blockIdx.x] = s[511];
}

__global__ void __launch_bounds__(512) genscan2(int* __restrict__ bsums, int nb) {
    __shared__ int s[512];
    int tid = threadIdx.x;
    int v = (tid < nb) ? bsums[tid] : 0;
    s[tid] = v;
    __syncthreads();
    for (int d = 1; d < 512; d <<= 1) {
        int t = (tid >= d) ? s[tid - d] : 0;
        __syncthreads();
        s[tid] += t;
        __syncthreads();
    }
    if (tid < nb) bsums[tid] = s[tid] - v;
}

__global__ void __launch_bounds__(512) genscan3(int* __restrict__ a, const int* __restrict__ bsums, int n) {
    int i = blockIdx.x * 512 + threadIdx.x;
    if (i < n) a[i] += bsums[blockIdx.x];
}

// ---------- per-chunk bin histogram ----------
// pass1: key = srcs[i] >> SHIFT ; pass2: key = pairs[i].y >> SHIFT
template <int NBIN, int SHIFT, bool FROMPAIR>
__global__ void k_bin_hist(const int* __restrict__ keysrc, const int2* __restrict__ pairs,
                           int* __restrict__ hist, int e, int nb) {
    __shared__ int h[NBIN];
    for (int i = threadIdx.x; i < NBIN; i += 256) h[i] = 0;
    __syncthreads();
    int base = blockIdx.x * CHUNK;
    for (int k = threadIdx.x; k < CHUNK; k += 256) {
        int idx = base + k;
        if (idx < e) {
            int key = FROMPAIR ? pairs[idx].y : keysrc[idx];
            atomicAdd(&h[key >> SHIFT], 1);
        }
    }
    __syncthreads();
    for (int b = threadIdx.x; b < NBIN; b += 256) hist[b * nb + blockIdx.x] = h[b];
}

// ---------- LDS-staged counting-sort scatter (coalesced run writes) ----------
template <int NBIN, int SHIFT, bool KEYX, bool FROMPAIR>
__global__ void k_bin_scatter(const int* __restrict__ srcs, const int* __restrict__ dsts,
                              const int2* __restrict__ pairs_in, const int* __restrict__ offsets,
                              int2* __restrict__ outbuf, int e, int nb) {
    __shared__ int hcnt[NBIN];     // counts -> cursor
    __shared__ int lstart[NBIN];   // local start -> delta
    __shared__ int ss[256];
    __shared__ int2 stage[CHUNK];
    int tid = threadIdx.x, blk = blockIdx.x, base = blk * CHUNK;
    int lim = e - base; if (lim > CHUNK) lim = CHUNK;
    for (int i = tid; i < NBIN; i += 256) hcnt[i] = 0;
    __syncthreads();
    for (int k = tid; k < lim; k += 256) {
        int2 ed = FROMPAIR ? pairs_in[base + k] : make_int2(srcs[base + k], dsts[base + k]);
        int b = (KEYX ? ed.x : ed.y) >> SHIFT;
        atomicAdd(&hcnt[b], 1);
    }
    __syncthreads();
    // exclusive scan of hcnt -> lstart  (thread owns R consecutive bins)
    const int R = NBIN / 256;
    int loc[R]; int sum = 0;
    #pragma unroll
    for (int r = 0; r < R; r++) { loc[r] = sum; sum += hcnt[tid * R + r]; }
    ss[tid] = sum;
    __syncthreads();
    for (int d = 1; d < 256; d <<= 1) {
        int t = (tid >= d) ? ss[tid - d] : 0;
        __syncthreads();
        ss[tid] += t;
        __syncthreads();
    }
    int excl = ss[tid] - sum;
    #pragma unroll
    for (int r = 0; r < R; r++) lstart[tid * R + r] = excl + loc[r];
    __syncthreads();
    for (int i = tid; i < NBIN; i += 256) hcnt[i] = lstart[i];  // cursors
    __syncthreads();
    // rank + stage into LDS grouped by bin
    for (int k = tid; k < lim; k += 256) {
        int2 ed = FROMPAIR ? pairs_in[base + k] : make_int2(srcs[base + k], dsts[base + k]);
        int b = (KEYX ? ed.x : ed.y) >> SHIFT;
        int p = atomicAdd(&hcnt[b], 1);
        stage[p] = ed;
    }
    __syncthreads();
    // delta[b] = global_start - local_start; then write runs coalesced
    for (int i = tid; i < NBIN; i += 256) lstart[i] = offsets[i * nb + blk] - lstart[i];
    __syncthreads();
    for (int p = tid; p < lim; p += 256) {
        int2 ed = stage[p];
        int b = (KEYX ? ed.x : ed.y) >> SHIFT;
        outbuf[lstart[b] + p] = ed;
    }
}

// ---------- layer-1 binned pull on raw 2-feature x ----------
// edges sorted by (dst>>7 major); block per 128-node bin, LDS accumulate
__global__ void k_pull2_bin(const int2* __restrict__ edges, const int* __restrict__ offsets2,
                            const float* __restrict__ x, const float* __restrict__ dinv,
                            float* __restrict__ aggx, int n, int nb, int e_total) {
    __shared__ float acc[128 * 2];
    int bin = blockIdx.x, tid = threadIdx.x, n0 = bin << 7;
    acc[tid] = 0.0f;   // blockDim = 256 covers all 256 slots
    __syncthreads();
    int e0 = offsets2[bin * nb];
    int e1 = (bin + 1 < 1024) ? offsets2[(bin + 1) * nb] : e_total;
    const float2* x2 = (const float2*)x;
    for (int i = e0 + tid; i < e1; i += 256) {
        int2 ed = edges[i];
        float w = dinv[ed.x] * dinv[ed.y];
        float2 v = x2[ed.x];
        int dl = (ed.y - n0) * 2;
        atomicAdd(&acc[dl], w * v.x);
        atomicAdd(&acc[dl + 1], w * v.y);
    }
    __syncthreads();
    int node = n0 + (tid >> 1);
    if (node < n) {
        float dd = dinv[node];
        float xv = x[node * 2 + (tid & 1)];
        aggx[node * 2 + (tid & 1)] = acc[tid] + dd * dd * xv;
    }
}

// h1 = relu(aggx @ W1 + b1) -> bf16
__global__ void k_lin1(const float* __restrict__ aggx, const float* __restrict__ W1,
                       const float* __restrict__ b1, __hip_bfloat16* __restrict__ h, int n) {
    int t = blockIdx.x * blockDim.x + threadIdx.x;
    if (t < n * 64) {
        int i = t >> 6, j = t & 63;
        float v = aggx[2 * i] * W1[j] + aggx[2 * i + 1] * W1[64 + j] + b1[j];
        h[t] = __float2bfloat16(fmaxf(v, 0.0f));
    }
}

// ---------- binned width-64 aggregation: block per 128-node bin ----------
__global__ void __launch_bounds__(512) k_agg_bin(const int2* __restrict__ edges,
                                                 const int* __restrict__ offsets2,
                                                 const __hip_bfloat16* __restrict__ h,
                                                 const float* __restrict__ dinv,
                                                 __hip_bfloat16* __restrict__ outp,
                                                 int n, int nb, int e_total) {
    __shared__ float acc[128 * 64];  // 32 KB
    int bin = blockIdx.x, tid = threadIdx.x, n0 = bin << 7;
    for (int i = tid; i < 128 * 64; i += 512) acc[i] = 0.0f;
    __syncthreads();
    int e0 = offsets2[bin * nb];
    int e1 = (bin + 1 < 1024) ? offsets2[(bin + 1) * nb] : e_total;
    int wave = tid >> 6, lane = tid & 63;
    for (int basei = e0 + (wave << 6); basei < e1; basei += 512) {
        int idx = basei + lane;
        int sl = 0, dl = 0; float wl = 0.0f;
        if (idx < e1) {
            int2 ed = edges[idx];                       // coalesced
            sl = ed.x; dl = ed.y - n0;
            wl = dinv[ed.x] * dinv[ed.y];               // near-sequential gathers
        }
        int take = e1 - basei; if (take > 64) take = 64;
        int take4 = (take + 3) & ~3;
        for (int k = 0; k < take4; k += 4) {
            int   s0 = __shfl(sl, k),     s1 = __shfl(sl, k + 1);
            int   s2 = __shfl(sl, k + 2), s3 = __shfl(sl, k + 3);
            int   d0 = __shfl(dl, k),     d1 = __shfl(dl, k + 1);
            int   d2 = __shfl(dl, k + 2), d3 = __shfl(dl, k + 3);
            float w0 = __shfl(wl, k),     w1 = __shfl(wl, k + 1);
            float w2 = __shfl(wl, k + 2), w3 = __shfl(wl, k + 3);
            float v0 = bf2f(h[(size_t)s0 * 64 + lane]);
            float v1 = bf2f(h[(size_t)s1 * 64 + lane]);
            float v2 = bf2f(h[(size_t)s2 * 64 + lane]);
            float v3 = bf2f(h[(size_t)s3 * 64 + lane]);
            atomicAdd(&acc[(d0 << 6) + lane], w0 * v0);   // pad lanes: w=0, d=0 -> +0
            atomicAdd(&acc[(d1 << 6) + lane], w1 * v1);
            atomicAdd(&acc[(d2 << 6) + lane], w2 * v2);
            atomicAdd(&acc[(d3 << 6) + lane], w3 * v3);
        }
    }
    __syncthreads();
    for (int p = tid; p < 128 * 64; p += 512) {
        int node = n0 + (p >> 6);
        if (node < n) {
            float dd = dinv[node];
            float v = acc[p] + dd * dd * bf2f(h[(size_t)node * 64 + (p & 63)]);
            outp[(size_t)node * 64 + (p & 63)] = __float2bfloat16(v);
        }
    }
}

// ---------- pack W (64x64 fp32) into MFMA B-fragment order, bf16 ----------
__global__ void k_prepW(const float* __restrict__ W2, const float* __restrict__ W3,
                        __hip_bfloat16* __restrict__ Wf2, __hip_bfloat16* __restrict__ Wf3) {
    const float* W = blockIdx.x ? W3 : W2;
    __hip_bfloat16* Wf = blockIdx.x ? Wf3 : Wf2;
    int t = threadIdx.x;           // 0..511
    int c = t >> 6, l = t & 63;
    int jt = c >> 1, half = c & 1, nn = l & 15, q = l >> 4;
    #pragma unroll
    for (int j = 0; j < 8; j++) {
        int k = half * 32 + q * 8 + j;
        Wf[t * 8 + j] = __float2bfloat16(W[k * 64 + jt * 16 + nn]);
    }
}

// ---------- MFMA linear: out = act(in @ W + b); wave = 16 nodes ----------
template <int RELU>
__global__ void k_linM(const __hip_bfloat16* __restrict__ in,
                       const __hip_bfloat16* __restrict__ Wf,
                       const float* __restrict__ b,
                       __hip_bfloat16* __restrict__ out16, int n) {
    int wave = threadIdx.x >> 6, lane = threadIdx.x & 63;
    int nb = (blockIdx.x * (blockDim.x >> 6) + wave) * 16;
    if (nb >= n) return;
    int m = lane & 15, q = lane >> 4;
    int arow = nb + m; if (arow >= n) arow = n - 1;
    short8 a0 = *reinterpret_cast<const short8*>(in + (size_t)arow * 64 + q * 8);
    short8 a1 = *reinterpret_cast<const short8*>(in + (size_t)arow * 64 + 32 + q * 8);
    #pragma unroll
    for (int jt = 0; jt < 4; jt++) {
        short8 bf0 = *reinterpret_cast<const short8*>(Wf + ((size_t)(jt * 2 + 0) * 64 + lane) * 8);
        short8 bf1 = *reinterpret_cast<const short8*>(Wf + ((size_t)(jt * 2 + 1) * 64 + lane) * 8);
        float4v d = {0.0f, 0.0f, 0.0f, 0.0f};
        d = __builtin_amdgcn_mfma_f32_16x16x32_bf16(a0, bf0, d, 0, 0, 0);
        d = __builtin_amdgcn_mfma_f32_16x16x32_bf16(a1, bf1, d, 0, 0, 0);
        float bias = b[jt * 16 + m];           // C/D col = lane&15
        #pragma unroll
        for (int r = 0; r < 4; r++) {
            int row = q * 4 + r;               // C/D row = quad*4 + reg
            int node = nb + row;
            if (node < n) {
                float v = d[r] + bias;
                if (RELU) v = fmaxf(v, 0.0f);
                out16[(size_t)node * 64 + jt * 16 + m] = __float2bfloat16(v);
            }
        }
    }
}

// ---------- node-parallel pool ----------
__global__ void k_pool_par(const __hip_bfloat16* __restrict__ h,
                           const int* __restrict__ batch,
                           float* __restrict__ sums, int n) {
    int base = blockIdx.x * 128;
    int lim = base + 128; if (lim > n) lim = n;
    int j = threadIdx.x & 63, r = threadIdx.x >> 6;
    float acc = 0.0f; int gcur = -1;
    for (int i = base + r; i < lim; i += 4) {
        int g = batch[i];
        if (g != gcur) {
            if (gcur >= 0) atomicAdd(&sums[gcur * 64 + j], acc);
            acc = 0.0f; gcur = g;
        }
        acc += bf2f(h[(size_t)i * 64 + j]);
    }
    if (gcur >= 0) atomicAdd(&sums[gcur * 64 + j], acc);
}

// ---------- head ----------
__device__ inline int lower_bound_i(const int* __restrict__ a, int n, int key) {
    int lo = 0, hi = n;
    while (lo < hi) {
        int mid = (lo + hi) >> 1;
        if (a[mid] < key) lo = mid + 1; else hi = mid;
    }
    return lo;
}

__global__ void k_head(const float* __restrict__ sums, const int* __restrict__ batch,
                       const float* __restrict__ ge, const float* __restrict__ Wl,
                       const float* __restrict__ bl, float* __restrict__ out,
                       int n, int ng) {
    int g = blockIdx.x * blockDim.x + threadIdx.x;
    if (g < ng) {
        int lo = lower_bound_i(batch, n, g);
        int hi = lower_bound_i(batch, n, g + 1);
        float c = fmaxf((float)(hi - lo), 1.0f);
        float z[5];
        for (int cl = 0; cl < 5; cl++) z[cl] = bl[cl];
        for (int k = 0; k < 64; k++) {
            float p = sums[g * 64 + k] / c;
            for (int cl = 0; cl < 5; cl++) z[cl] += p * Wl[k * 5 + cl];
        }
        for (int k = 0; k < 64; k++) {
            float p = ge[g * 64 + k];
            for (int cl = 0; cl < 5; cl++) z[cl] += p * Wl[(64 + k) * 5 + cl];
        }
        float m = z[0];
        for (int cl = 1; cl < 5; cl++) m = fmaxf(m, z[cl]);
        float s = 0.0f;
        for (int cl = 0; cl < 5; cl++) s += expf(z[cl] - m);
        float lse = m + logf(s);
        for (int cl = 0; cl < 5; cl++) out[g * 5 + cl] = z[cl] - lse;
    }
}

#define ALIGN16(x) (((x) + 15) & ~(size_t)15)

extern "C" void kernel_launch(void* const* d_in, const int* in_sizes, int n_in,
                              void* d_out, int out_size, void* d_ws, size_t ws_size,
                              hipStream_t stream) {
    const float* x    = (const float*)d_in[0];
    const int*   ei   = (const int*)d_in[1];
    const int*   batch= (const int*)d_in[2];
    const float* ge   = (const float*)d_in[3];
    const float* W1   = (const float*)d_in[4];
    const float* b1   = (const float*)d_in[5];
    const float* W2   = (const float*)d_in[6];
    const float* b2   = (const float*)d_in[7];
    const float* W3   = (const float*)d_in[8];
    const float* b3   = (const float*)d_in[9];
    const float* Wl   = (const float*)d_in[10];
    const float* bl   = (const float*)d_in[11];
    float* out = (float*)d_out;

    const int N = in_sizes[0] / 2;   // x is [N,2]
    const int E = in_sizes[1] / 2;   // edge_index is [2,E]
    const int* src = ei;
    const int* dst = ei + E;

    const int nbC = (E + CHUNK - 1) / CHUNK;     // sort chunks (245)
    const int NB2 = (N + 127) >> 7;              // dst bins (782)

    // ---- workspace layout ----
    char* wsb = (char*)d_ws;
    float* dinv   = (float*)wsb;                wsb += ALIGN16((size_t)N * 4);
    float* aggx   = (float*)wsb;                wsb += ALIGN16((size_t)2 * N * 4);
    __hip_bfloat16* h16  = (__hip_bfloat16*)wsb; wsb += ALIGN16((size_t)64 * N * 2);
    __hip_bfloat16* agg16= (__hip_bfloat16*)wsb; wsb += ALIGN16((size_t)64 * N * 2);
    float* sums   = (float*)wsb;                wsb += ALIGN16((size_t)NG * 64 * 4);
    __hip_bfloat16* Wf2 = (__hip_bfloat16*)wsb; wsb += ALIGN16((size_t)4096 * 2);
    __hip_bfloat16* Wf3 = (__hip_bfloat16*)wsb; wsb += ALIGN16((size_t)4096 * 2);
    int2*  e1buf  = (int2*)wsb;                 wsb += ALIGN16((size_t)E * 8);
    int2*  e2buf  = (int2*)wsb;                 wsb += ALIGN16((size_t)E * 8);
    int*   counts = (int*)wsb;                  wsb += ALIGN16((size_t)N * 4);
    int*   hist1  = (int*)wsb;                  wsb += ALIGN16((size_t)512 * nbC * 4);
    int*   hist2  = (int*)wsb;                  wsb += ALIGN16((size_t)1024 * nbC * 4);
    int*   bsums  = (int*)wsb;                  wsb += 512 * 4;

    const int BS = 256;
    int gN   = (N + BS - 1) / BS;
    int gE   = (E + BS - 1) / BS;
    int gN64 = (N * 64 + BS - 1) / BS;
    int gM   = ((N + 15) / 16 + 3) / 4;
    int gP   = (N + 127) / 128;
    int n1 = 512 * nbC,  g1 = (n1 + 511) / 512;
    int n2 = 1024 * nbC, g2 = (n2 + 511) / 512;

    // ---- degrees ----
    hipMemsetAsync(counts, 0, (size_t)N * 4, stream);
    hipMemsetAsync(sums, 0, (size_t)NG * 64 * 4, stream);
    k_hist<<<gE, BS, 0, stream>>>(dst, counts, E);
    k_dinv_ew<<<gN, BS, 0, stream>>>(counts, dinv, N);

    // ---- pass 1: sort by src-bucket (src>>8, 512 bins) ----
    k_bin_hist<512, 8, false><<<nbC, BS, 0, stream>>>(src, nullptr, hist1, E, nbC);
    genscan1<<<g1, 512, 0, stream>>>(hist1, bsums, n1);
    genscan2<<<1, 512, 0, stream>>>(bsums, g1);
    genscan3<<<g1, 512, 0, stream>>>(hist1, bsums, n1);
    k_bin_scatter<512, 8, true, false><<<nbC, BS, 0, stream>>>(src, dst, nullptr, hist1, e1buf, E, nbC);

    // ---- pass 2: stable sort by dst-bin (dst>>7, 1024 bins) ----
    k_bin_hist<1024, 7, true><<<nbC, BS, 0, stream>>>(nullptr, e1buf, hist2, E, nbC);
    genscan1<<<g2, 512, 0, stream>>>(hist2, bsums, n2);
    genscan2<<<1, 512, 0, stream>>>(bsums, g2);
    genscan3<<<g2, 512, 0, stream>>>(hist2, bsums, n2);
    k_bin_scatter<1024, 7, false, true><<<nbC, BS, 0, stream>>>(nullptr, nullptr, e1buf, hist2, e2buf, E, nbC);

    k_prepW<<<2, 512, 0, stream>>>(W2, W3, Wf2, Wf3);

    // ---- layer 1 ----
    k_pull2_bin<<<NB2, BS, 0, stream>>>(e2buf, hist2, x, dinv, aggx, N, nbC, E);
    k_lin1<<<gN64, BS, 0, stream>>>(aggx, W1, b1, h16, N);

    // ---- layer 2 ----
    k_agg_bin<<<NB2, 512, 0, stream>>>(e2buf, hist2, h16, dinv, agg16, N, nbC, E);
    k_linM<1><<<gM, BS, 0, stream>>>(agg16, Wf2, b2, h16, N);

    // ---- layer 3 ----
    k_agg_bin<<<NB2, 512, 0, stream>>>(e2buf, hist2, h16, dinv, agg16, N, nbC, E);
    k_linM<0><<<gM, BS, 0, stream>>>(agg16, Wf3, b3, h16, N);

    // ---- pool + head ----
    k_pool_par<<<gP, BS, 0, stream>>>(h16, batch, sums, N);
    k_head<<<1, 128, 0, stream>>>(sums, batch, ge, Wl, bl, out, N, NG);
}

// Round 7
// 364.362 us; speedup vs baseline: 3.3290x; 3.3290x over previous
//
#include <hip/hip_runtime.h>
#include <hip/hip_bf16.h>
#include <math.h>

#define NG 128

typedef __attribute__((ext_vector_type(8))) short short8;
typedef __attribute__((ext_vector_type(4))) float float4v;

static __device__ __forceinline__ float bf2f(__hip_bfloat16 v) { return __bfloat162float(v); }

// ---------- CSR build ----------
__global__ void k_hist(const int* __restrict__ dst, int* __restrict__ counts, int e) {
    int i = blockIdx.x * blockDim.x + threadIdx.x;
    if (i < e) atomicAdd(&counts[dst[i]], 1);
}

__global__ void k_scan1(const int* __restrict__ counts, int* __restrict__ row_ptr,
                        int* __restrict__ blk_sums, int n) {
    __shared__ int s[256];
    int tid = threadIdx.x;
    int i = blockIdx.x * 256 + tid;
    int v = (i < n) ? counts[i] : 0;
    s[tid] = v;
    __syncthreads();
    for (int d = 1; d < 256; d <<= 1) {
        int t = (tid >= d) ? s[tid - d] : 0;
        __syncthreads();
        s[tid] += t;
        __syncthreads();
    }
    if (i < n) row_ptr[i] = s[tid] - v;  // exclusive
    if (tid == 255) blk_sums[blockIdx.x] = s[255];
}

__global__ void k_scan2(int* __restrict__ blk_sums, int nb) {
    __shared__ int s[512];
    int tid = threadIdx.x;
    int v = (tid < nb) ? blk_sums[tid] : 0;
    s[tid] = v;
    __syncthreads();
    for (int d = 1; d < 512; d <<= 1) {
        int t = (tid >= d) ? s[tid - d] : 0;
        __syncthreads();
        s[tid] += t;
        __syncthreads();
    }
    if (tid < nb) blk_sums[tid] = s[tid] - v;  // exclusive
}

__global__ void k_scan3(int* __restrict__ row_ptr, const int* __restrict__ blk_sums,
                        const int* __restrict__ counts, int* __restrict__ cursor,
                        float* __restrict__ dinv, int n, int e_total) {
    int i = blockIdx.x * 256 + threadIdx.x;
    if (i < n) {
        int v = row_ptr[i] + blk_sums[blockIdx.x];
        row_ptr[i] = v;
        cursor[i] = v;
        dinv[i] = rsqrtf((float)counts[i] + 1.0f);  // +1 self-loop
        if (i == n - 1) row_ptr[n] = e_total;
    }
}

// scatter only src (4B payload): halves random-write bytes vs (src,w) int2;
// consumers recompute w from L2-resident dinv[]
__global__ void k_scatter(const int* __restrict__ src, const int* __restrict__ dst,
                          int* __restrict__ cursor, int* __restrict__ csr_src, int e) {
    int i = blockIdx.x * blockDim.x + threadIdx.x;
    if (i < e) {
        int s = src[i], d = dst[i];
        int pos = atomicAdd(&cursor[d], 1);
        csr_src[pos] = s;
    }
}

// ---------- layer-1 pull on raw 2-feature x (thread per node, 4x unroll) ----------
__global__ void k_pull2(const int* __restrict__ row_ptr, const int* __restrict__ csr_src,
                        const float* __restrict__ x, const float* __restrict__ dinv,
                        float* __restrict__ out, int n) {
    int i = blockIdx.x * blockDim.x + threadIdx.x;
    if (i < n) {
        const float2* x2 = (const float2*)x;
        float dd = dinv[i], d2 = dd * dd;
        float2 xi = x2[i];
        float a0 = d2 * xi.x, a1 = d2 * xi.y;
        int lo = row_ptr[i], hi = row_ptr[i + 1];
        int k = lo;
        for (; k + 4 <= hi; k += 4) {
            int s0 = csr_src[k], s1 = csr_src[k + 1], s2 = csr_src[k + 2], s3 = csr_src[k + 3];
            float w0 = dinv[s0] * dd, w1 = dinv[s1] * dd, w2 = dinv[s2] * dd, w3 = dinv[s3] * dd;
            float2 v0 = x2[s0], v1 = x2[s1], v2 = x2[s2], v3 = x2[s3];
            a0 += w0 * v0.x; a1 += w0 * v0.y;
            a0 += w1 * v1.x; a1 += w1 * v1.y;
            a0 += w2 * v2.x; a1 += w2 * v2.y;
            a0 += w3 * v3.x; a1 += w3 * v3.y;
        }
        for (; k < hi; k++) {
            int s = csr_src[k];
            float w = dinv[s] * dd;
            float2 v = x2[s];
            a0 += w * v.x;
            a1 += w * v.y;
        }
        out[2 * i] = a0;
        out[2 * i + 1] = a1;
    }
}

// h1 = relu(aggx @ W1 + b1) -> bf16
__global__ void k_lin1(const float* __restrict__ aggx, const float* __restrict__ W1,
                       const float* __restrict__ b1, __hip_bfloat16* __restrict__ h, int n) {
    int t = blockIdx.x * blockDim.x + threadIdx.x;
    if (t < n * 64) {
        int i = t >> 6, j = t & 63;
        float v = aggx[2 * i] * W1[j] + aggx[2 * i + 1] * W1[64 + j] + b1[j];
        h[t] = __float2bfloat16(fmaxf(v, 0.0f));
    }
}

// ---------- width-64 pull aggregation (bf16 gather, fp32 acc, 8-wide ILP) ----------
__global__ void k_agg(const int* __restrict__ row_ptr, const int* __restrict__ csr_src,
                      const __hip_bfloat16* __restrict__ h, const float* __restrict__ dinv,
                      __hip_bfloat16* __restrict__ out, int n) {
    int node = blockIdx.x * (blockDim.x >> 6) + (threadIdx.x >> 6);
    int lane = threadIdx.x & 63;
    if (node >= n) return;
    float dn = dinv[node];
    float acc = dn * dn * bf2f(h[(size_t)node * 64 + lane]);
    int lo = row_ptr[node], hi = row_ptr[node + 1];
    for (int base = lo; base < hi; base += 64) {
        int take = hi - base; if (take > 64) take = 64;
        int take8 = (take + 7) & ~7;     // pad to 8; pad lanes carry w=0, s=0
        int sl = 0; float wl = 0.0f;
        if (base + lane < hi) {
            sl = csr_src[base + lane];          // coalesced
            wl = dinv[sl] * dn;                 // L2-resident gather
        }
        for (int k = 0; k < take8; k += 8) {
            int   s0 = __shfl(sl, k),     s1 = __shfl(sl, k + 1);
            int   s2 = __shfl(sl, k + 2), s3 = __shfl(sl, k + 3);
            int   s4 = __shfl(sl, k + 4), s5 = __shfl(sl, k + 5);
            int   s6 = __shfl(sl, k + 6), s7 = __shfl(sl, k + 7);
            float w0 = __shfl(wl, k),     w1 = __shfl(wl, k + 1);
            float w2 = __shfl(wl, k + 2), w3 = __shfl(wl, k + 3);
            float w4 = __shfl(wl, k + 4), w5 = __shfl(wl, k + 5);
            float w6 = __shfl(wl, k + 6), w7 = __shfl(wl, k + 7);
            float v0 = bf2f(h[(size_t)s0 * 64 + lane]);
            float v1 = bf2f(h[(size_t)s1 * 64 + lane]);
            float v2 = bf2f(h[(size_t)s2 * 64 + lane]);
            float v3 = bf2f(h[(size_t)s3 * 64 + lane]);
            float v4 = bf2f(h[(size_t)s4 * 64 + lane]);
            float v5 = bf2f(h[(size_t)s5 * 64 + lane]);
            float v6 = bf2f(h[(size_t)s6 * 64 + lane]);
            float v7 = bf2f(h[(size_t)s7 * 64 + lane]);
            acc += w0 * v0; acc += w1 * v1; acc += w2 * v2; acc += w3 * v3;
            acc += w4 * v4; acc += w5 * v5; acc += w6 * v6; acc += w7 * v7;
        }
    }
    out[(size_t)node * 64 + lane] = __float2bfloat16(acc);
}

// ---------- pack W (64x64 fp32) into MFMA B-fragment order, bf16 ----------
__global__ void k_prepW(const float* __restrict__ W2, const float* __restrict__ W3,
                        __hip_bfloat16* __restrict__ Wf2, __hip_bfloat16* __restrict__ Wf3) {
    const float* W = blockIdx.x ? W3 : W2;
    __hip_bfloat16* Wf = blockIdx.x ? Wf3 : Wf2;
    int t = threadIdx.x;           // 0..511
    int c = t >> 6, l = t & 63;
    int jt = c >> 1, half = c & 1, nn = l & 15, q = l >> 4;
    #pragma unroll
    for (int j = 0; j < 8; j++) {
        int k = half * 32 + q * 8 + j;
        Wf[t * 8 + j] = __float2bfloat16(W[k * 64 + jt * 16 + nn]);
    }
}

// ---------- MFMA linear: out = act(in @ W + b); wave = 16 nodes ----------
template <int RELU>
__global__ void k_linM(const __hip_bfloat16* __restrict__ in,
                       const __hip_bfloat16* __restrict__ Wf,
                       const float* __restrict__ b,
                       __hip_bfloat16* __restrict__ out16, int n) {
    int wave = threadIdx.x >> 6, lane = threadIdx.x & 63;
    int nb = (blockIdx.x * (blockDim.x >> 6) + wave) * 16;
    if (nb >= n) return;
    int m = lane & 15, q = lane >> 4;
    int arow = nb + m; if (arow >= n) arow = n - 1;
    short8 a0 = *reinterpret_cast<const short8*>(in + (size_t)arow * 64 + q * 8);
    short8 a1 = *reinterpret_cast<const short8*>(in + (size_t)arow * 64 + 32 + q * 8);
    #pragma unroll
    for (int jt = 0; jt < 4; jt++) {
        short8 bf0 = *reinterpret_cast<const short8*>(Wf + ((size_t)(jt * 2 + 0) * 64 + lane) * 8);
        short8 bf1 = *reinterpret_cast<const short8*>(Wf + ((size_t)(jt * 2 + 1) * 64 + lane) * 8);
        float4v d = {0.0f, 0.0f, 0.0f, 0.0f};
        d = __builtin_amdgcn_mfma_f32_16x16x32_bf16(a0, bf0, d, 0, 0, 0);
        d = __builtin_amdgcn_mfma_f32_16x16x32_bf16(a1, bf1, d, 0, 0, 0);
        float bias = b[jt * 16 + m];           // C/D col = lane&15
        #pragma unroll
        for (int r = 0; r < 4; r++) {
            int row = q * 4 + r;               // C/D row = quad*4 + reg
            int node = nb + row;
            if (node < n) {
                float v = d[r] + bias;
                if (RELU) v = fmaxf(v, 0.0f);
                out16[(size_t)node * 64 + jt * 16 + m] = __float2bfloat16(v);
            }
        }
    }
}

// ---------- node-parallel pool ----------
__global__ void k_pool_par(const __hip_bfloat16* __restrict__ h,
                           const int* __restrict__ batch,
                           float* __restrict__ sums, int n) {
    int base = blockIdx.x * 128;
    int lim = base + 128; if (lim > n) lim = n;
    int j = threadIdx.x & 63, r = threadIdx.x >> 6;
    float acc = 0.0f; int gcur = -1;
    for (int i = base + r; i < lim; i += 4) {
        int g = batch[i];
        if (g != gcur) {
            if (gcur >= 0) atomicAdd(&sums[gcur * 64 + j], acc);
            acc = 0.0f; gcur = g;
        }
        acc += bf2f(h[(size_t)i * 64 + j]);
    }
    if (gcur >= 0) atomicAdd(&sums[gcur * 64 + j], acc);
}

// ---------- head ----------
__device__ inline int lower_bound_i(const int* __restrict__ a, int n, int key) {
    int lo = 0, hi = n;
    while (lo < hi) {
        int mid = (lo + hi) >> 1;
        if (a[mid] < key) lo = mid + 1; else hi = mid;
    }
    return lo;
}

__global__ void k_head(const float* __restrict__ sums, const int* __restrict__ batch,
                       const float* __restrict__ ge, const float* __restrict__ Wl,
                       const float* __restrict__ bl, float* __restrict__ out,
                       int n, int ng) {
    int g = blockIdx.x * blockDim.x + threadIdx.x;
    if (g < ng) {
        int lo = lower_bound_i(batch, n, g);
        int hi = lower_bound_i(batch, n, g + 1);
        float c = fmaxf((float)(hi - lo), 1.0f);
        float z[5];
        for (int cl = 0; cl < 5; cl++) z[cl] = bl[cl];
        for (int k = 0; k < 64; k++) {
            float p = sums[g * 64 + k] / c;
            for (int cl = 0; cl < 5; cl++) z[cl] += p * Wl[k * 5 + cl];
        }
        for (int k = 0; k < 64; k++) {
            float p = ge[g * 64 + k];
            for (int cl = 0; cl < 5; cl++) z[cl] += p * Wl[(64 + k) * 5 + cl];
        }
        float m = z[0];
        for (int cl = 1; cl < 5; cl++) m = fmaxf(m, z[cl]);
        float s = 0.0f;
        for (int cl = 0; cl < 5; cl++) s += expf(z[cl] - m);
        float lse = m + logf(s);
        for (int cl = 0; cl < 5; cl++) out[g * 5 + cl] = z[cl] - lse;
    }
}

#define ALIGN16(x) (((x) + 15) & ~(size_t)15)

extern "C" void kernel_launch(void* const* d_in, const int* in_sizes, int n_in,
                              void* d_out, int out_size, void* d_ws, size_t ws_size,
                              hipStream_t stream) {
    const float* x    = (const float*)d_in[0];
    const int*   ei   = (const int*)d_in[1];
    const int*   batch= (const int*)d_in[2];
    const float* ge   = (const float*)d_in[3];
    const float* W1   = (const float*)d_in[4];
    const float* b1   = (const float*)d_in[5];
    const float* W2   = (const float*)d_in[6];
    const float* b2   = (const float*)d_in[7];
    const float* W3   = (const float*)d_in[8];
    const float* b3   = (const float*)d_in[9];
    const float* Wl   = (const float*)d_in[10];
    const float* bl   = (const float*)d_in[11];
    float* out = (float*)d_out;

    const int N = in_sizes[0] / 2;   // x is [N,2]
    const int E = in_sizes[1] / 2;   // edge_index is [2,E]
    const int* src = ei;
    const int* dst = ei + E;

    // ---- workspace layout (segments 16B-aligned) ----
    char* wsb = (char*)d_ws;
    float* dinv   = (float*)wsb;                wsb += ALIGN16((size_t)N * 4);
    float* aggx   = (float*)wsb;                wsb += ALIGN16((size_t)2 * N * 4);
    __hip_bfloat16* h16  = (__hip_bfloat16*)wsb; wsb += ALIGN16((size_t)64 * N * 2);  // h1 -> h2 -> h3
    __hip_bfloat16* agg16= (__hip_bfloat16*)wsb; wsb += ALIGN16((size_t)64 * N * 2);
    float* sums   = (float*)wsb;                wsb += ALIGN16((size_t)NG * 64 * 4);
    __hip_bfloat16* Wf2 = (__hip_bfloat16*)wsb; wsb += ALIGN16((size_t)4096 * 2);
    __hip_bfloat16* Wf3 = (__hip_bfloat16*)wsb; wsb += ALIGN16((size_t)4096 * 2);
    int*   csr_src= (int*)wsb;                  wsb += ALIGN16((size_t)E * 4);
    int*   counts = (int*)wsb;                  wsb += ALIGN16((size_t)N * 4);
    int*   cursor = (int*)wsb;                  wsb += ALIGN16((size_t)N * 4);
    int*   row_ptr= (int*)wsb;                  wsb += ALIGN16((size_t)(N + 1) * 4);
    int*   blk_sums=(int*)wsb;                  wsb += 512 * 4;

    const int BS = 256;
    int gN   = (N + BS - 1) / BS;
    int gE   = (E + BS - 1) / BS;
    int gN64 = (N * 64 + BS - 1) / BS;
    int gW   = (N + 3) / 4;                      // k_agg: 4 waves per block
    int gM   = ((N + 15) / 16 + 3) / 4;          // k_linM: 4 waves * 16 nodes
    int gP   = (N + 127) / 128;                  // pool chunks

    // ---- CSR build ----
    hipMemsetAsync(counts, 0, (size_t)N * 4, stream);
    hipMemsetAsync(sums, 0, (size_t)NG * 64 * 4, stream);
    k_hist<<<gE, BS, 0, stream>>>(dst, counts, E);
    k_scan1<<<gN, BS, 0, stream>>>(counts, row_ptr, blk_sums, N);
    k_scan2<<<1, 512, 0, stream>>>(blk_sums, gN);
    k_scan3<<<gN, BS, 0, stream>>>(row_ptr, blk_sums, counts, cursor, dinv, N, E);
    k_scatter<<<gE, BS, 0, stream>>>(src, dst, cursor, csr_src, E);
    k_prepW<<<2, 512, 0, stream>>>(W2, W3, Wf2, Wf3);

    // ---- layer 1 ----
    k_pull2<<<gN, BS, 0, stream>>>(row_ptr, csr_src, x, dinv, aggx, N);
    k_lin1<<<gN64, BS, 0, stream>>>(aggx, W1, b1, h16, N);

    // ---- layer 2: agg = A@h1 ; h2 = relu(agg@W2+b2) (overwrites h1) ----
    k_agg<<<gW, BS, 0, stream>>>(row_ptr, csr_src, h16, dinv, agg16, N);
    k_linM<1><<<gM, BS, 0, stream>>>(agg16, Wf2, b2, h16, N);

    // ---- layer 3: agg = A@h2 ; h3 = agg@W3+b3 -> bf16 (overwrites h2) ----
    k_agg<<<gW, BS, 0, stream>>>(row_ptr, csr_src, h16, dinv, agg16, N);
    k_linM<0><<<gM, BS, 0, stream>>>(agg16, Wf3, b3, h16, N);

    // ---- pool + head ----
    k_pool_par<<<gP, BS, 0, stream>>>(h16, batch, sums, N);
    k_head<<<1, 128, 0, stream>>>(sums, batch, ge, Wl, bl, out, N, NG);
}

// Round 8
// 316.857 us; speedup vs baseline: 3.8281x; 1.1499x over previous
//
#include <hip/hip_runtime.h>
#include <hip/hip_bf16.h>
#include <math.h>

#define NG 128
#define CHUNKB 4096
#define MAXBUK 512   // >= ceil(N/256), N <= 131072

typedef __attribute__((ext_vector_type(8))) short short8;
typedef __attribute__((ext_vector_type(4))) float float4v;

static __device__ __forceinline__ float bf2f(__hip_bfloat16 v) { return __bfloat162float(v); }

// ---------- degree histogram ----------
__global__ void k_hist(const int* __restrict__ dst, int* __restrict__ counts, int e) {
    int i = blockIdx.x * blockDim.x + threadIdx.x;
    if (i < e) atomicAdd(&counts[dst[i]], 1);
}

__global__ void k_scan1(const int* __restrict__ counts, int* __restrict__ row_ptr,
                        int* __restrict__ blk_sums, int n) {
    __shared__ int s[256];
    int tid = threadIdx.x;
    int i = blockIdx.x * 256 + tid;
    int v = (i < n) ? counts[i] : 0;
    s[tid] = v;
    __syncthreads();
    for (int d = 1; d < 256; d <<= 1) {
        int t = (tid >= d) ? s[tid - d] : 0;
        __syncthreads();
        s[tid] += t;
        __syncthreads();
    }
    if (i < n) row_ptr[i] = s[tid] - v;  // exclusive
    if (tid == 255) blk_sums[blockIdx.x] = s[255];
}

__global__ void k_scan2(int* __restrict__ blk_sums, int nb) {
    __shared__ int s[512];
    int tid = threadIdx.x;
    int v = (tid < nb) ? blk_sums[tid] : 0;
    s[tid] = v;
    __syncthreads();
    for (int d = 1; d < 512; d <<= 1) {
        int t = (tid >= d) ? s[tid - d] : 0;
        __syncthreads();
        s[tid] += t;
        __syncthreads();
    }
    if (tid < nb) blk_sums[tid] = s[tid] - v;  // exclusive
}

__global__ void k_scan3(int* __restrict__ row_ptr, const int* __restrict__ blk_sums,
                        const int* __restrict__ counts, float* __restrict__ dinv,
                        int n, int e_total) {
    int i = blockIdx.x * 256 + threadIdx.x;
    if (i < n) {
        int v = row_ptr[i] + blk_sums[blockIdx.x];
        row_ptr[i] = v;
        dinv[i] = rsqrtf((float)counts[i] + 1.0f);  // +1 self-loop
        if (i == n - 1) row_ptr[n] = e_total;
    }
}

// bucket cursors = CSR offset of each 256-node bucket's start
__global__ void k_bcur(const int* __restrict__ row_ptr, int* __restrict__ bcur, int nbuk) {
    int b = blockIdx.x * blockDim.x + threadIdx.x;
    if (b < nbuk) bcur[b] = row_ptr[b << 8];
}

// ---------- Phase B: LDS-staged bucket scatter (clustered writes) ----------
__global__ void k_bucket(const int* __restrict__ src, const int* __restrict__ dst,
                         int* __restrict__ bcur, int2* __restrict__ ebuck,
                         int e, int nbuk) {
    __shared__ int hcnt[MAXBUK];
    __shared__ int hbase[MAXBUK];
    __shared__ int ss[256];
    __shared__ int2 stage[CHUNKB];
    int tid = threadIdx.x;
    int base = blockIdx.x * CHUNKB;
    int lim = e - base; if (lim > CHUNKB) lim = CHUNKB;
    for (int i = tid; i < MAXBUK; i += 256) hcnt[i] = 0;
    __syncthreads();
    for (int k = tid; k < lim; k += 256)
        atomicAdd(&hcnt[dst[base + k] >> 8], 1);
    __syncthreads();
    // scan (thread owns 2 bins)
    int c0 = hcnt[2 * tid], c1 = hcnt[2 * tid + 1];
    int sum = c0 + c1;
    ss[tid] = sum;
    __syncthreads();
    for (int d = 1; d < 256; d <<= 1) {
        int t = (tid >= d) ? ss[tid - d] : 0;
        __syncthreads();
        ss[tid] += t;
        __syncthreads();
    }
    int excl = ss[tid] - sum;
    hbase[2 * tid] = excl;
    hbase[2 * tid + 1] = excl + c0;
    __syncthreads();
    hcnt[2 * tid] = excl;          // cursors
    hcnt[2 * tid + 1] = excl + c0;
    __syncthreads();
    for (int k = tid; k < lim; k += 256) {
        int s = src[base + k], d = dst[base + k];
        int p = atomicAdd(&hcnt[d >> 8], 1);
        stage[p] = make_int2(s, d);
    }
    __syncthreads();
    // allocate global range per bucket; hbase[b] -> (global start - local start)
    for (int b = tid; b < nbuk; b += 256) {
        int cnt = hcnt[b] - hbase[b];
        int gstart = (cnt > 0) ? atomicAdd(&bcur[b], cnt) : 0;
        hbase[b] = gstart - hbase[b];
    }
    __syncthreads();
    // write each bucket's staged run contiguously
    for (int p = tid; p < lim; p += 256) {
        int2 ed = stage[p];
        ebuck[hbase[ed.y >> 8] + p] = ed;
    }
}

// ---------- Phase C: exact CSR within bucket; precompute w ----------
__global__ void k_csrfix(const int2* __restrict__ ebuck, const int* __restrict__ row_ptr,
                         const float* __restrict__ dinv, int2* __restrict__ csr,
                         int n, int nbuk) {
    __shared__ int lcnt[256];
    int b = blockIdx.x, tid = threadIdx.x;
    int n0 = b << 8;
    lcnt[tid] = 0;
    __syncthreads();
    int n1 = n0 + 256; if (n1 > n) n1 = n;
    int e0 = row_ptr[n0], e1 = row_ptr[n1];
    for (int i = e0 + tid; i < e1; i += 256) {
        int2 ed = ebuck[i];
        int r = atomicAdd(&lcnt[ed.y - n0], 1);
        int pos = row_ptr[ed.y] + r;
        float w = dinv[ed.x] * dinv[ed.y];
        csr[pos] = make_int2(ed.x, __float_as_int(w));
    }
}

// ---------- layer-1 pull on raw 2-feature x ----------
__global__ void k_pull2(const int* __restrict__ row_ptr, const int2* __restrict__ edges,
                        const float* __restrict__ x, const float* __restrict__ dinv,
                        float* __restrict__ out, int n) {
    int i = blockIdx.x * blockDim.x + threadIdx.x;
    if (i < n) {
        const float2* x2 = (const float2*)x;
        float dd = dinv[i], d2 = dd * dd;
        float2 xi = x2[i];
        float a0 = d2 * xi.x, a1 = d2 * xi.y;
        int lo = row_ptr[i], hi = row_ptr[i + 1];
        int k = lo;
        for (; k + 4 <= hi; k += 4) {
            int2 e0 = edges[k], e1 = edges[k + 1], e2 = edges[k + 2], e3 = edges[k + 3];
            float2 v0 = x2[e0.x], v1 = x2[e1.x], v2 = x2[e2.x], v3 = x2[e3.x];
            a0 += __int_as_float(e0.y) * v0.x; a1 += __int_as_float(e0.y) * v0.y;
            a0 += __int_as_float(e1.y) * v1.x; a1 += __int_as_float(e1.y) * v1.y;
            a0 += __int_as_float(e2.y) * v2.x; a1 += __int_as_float(e2.y) * v2.y;
            a0 += __int_as_float(e3.y) * v3.x; a1 += __int_as_float(e3.y) * v3.y;
        }
        for (; k < hi; k++) {
            int2 e = edges[k];
            float2 v = x2[e.x];
            a0 += __int_as_float(e.y) * v.x;
            a1 += __int_as_float(e.y) * v.y;
        }
        out[2 * i] = a0;
        out[2 * i + 1] = a1;
    }
}

// h1 = relu(aggx @ W1 + b1) -> bf16
__global__ void k_lin1(const float* __restrict__ aggx, const float* __restrict__ W1,
                       const float* __restrict__ b1, __hip_bfloat16* __restrict__ h, int n) {
    int t = blockIdx.x * blockDim.x + threadIdx.x;
    if (t < n * 64) {
        int i = t >> 6, j = t & 63;
        float v = aggx[2 * i] * W1[j] + aggx[2 * i + 1] * W1[64 + j] + b1[j];
        h[t] = __float2bfloat16(fmaxf(v, 0.0f));
    }
}

// ---------- width-64 pull aggregation (bf16 gather, fp32 acc, 8-wide ILP) ----------
__global__ void k_agg(const int* __restrict__ row_ptr, const int2* __restrict__ edges,
                      const __hip_bfloat16* __restrict__ h, const float* __restrict__ dinv,
                      __hip_bfloat16* __restrict__ out, int n) {
    int node = blockIdx.x * (blockDim.x >> 6) + (threadIdx.x >> 6);
    int lane = threadIdx.x & 63;
    if (node >= n) return;
    float dn = dinv[node];
    float acc = dn * dn * bf2f(h[(size_t)node * 64 + lane]);
    int lo = row_ptr[node], hi = row_ptr[node + 1];
    for (int base = lo; base < hi; base += 64) {
        int take = hi - base; if (take > 64) take = 64;
        int take8 = (take + 7) & ~7;     // pad lanes carry w=0, s=0
        int sl = 0; float wl = 0.0f;
        if (base + lane < hi) {
            int2 e = edges[base + lane];  // coalesced
            sl = e.x; wl = __int_as_float(e.y);
        }
        for (int k = 0; k < take8; k += 8) {
            int   s0 = __shfl(sl, k),     s1 = __shfl(sl, k + 1);
            int   s2 = __shfl(sl, k + 2), s3 = __shfl(sl, k + 3);
            int   s4 = __shfl(sl, k + 4), s5 = __shfl(sl, k + 5);
            int   s6 = __shfl(sl, k + 6), s7 = __shfl(sl, k + 7);
            float w0 = __shfl(wl, k),     w1 = __shfl(wl, k + 1);
            float w2 = __shfl(wl, k + 2), w3 = __shfl(wl, k + 3);
            float w4 = __shfl(wl, k + 4), w5 = __shfl(wl, k + 5);
            float w6 = __shfl(wl, k + 6), w7 = __shfl(wl, k + 7);
            float v0 = bf2f(h[(size_t)s0 * 64 + lane]);
            float v1 = bf2f(h[(size_t)s1 * 64 + lane]);
            float v2 = bf2f(h[(size_t)s2 * 64 + lane]);
            float v3 = bf2f(h[(size_t)s3 * 64 + lane]);
            float v4 = bf2f(h[(size_t)s4 * 64 + lane]);
            float v5 = bf2f(h[(size_t)s5 * 64 + lane]);
            float v6 = bf2f(h[(size_t)s6 * 64 + lane]);
            float v7 = bf2f(h[(size_t)s7 * 64 + lane]);
            acc += w0 * v0; acc += w1 * v1; acc += w2 * v2; acc += w3 * v3;
            acc += w4 * v4; acc += w5 * v5; acc += w6 * v6; acc += w7 * v7;
        }
    }
    out[(size_t)node * 64 + lane] = __float2bfloat16(acc);
}

// ---------- pack W (64x64 fp32) into MFMA B-fragment order, bf16 ----------
__global__ void k_prepW(const float* __restrict__ W2, const float* __restrict__ W3,
                        __hip_bfloat16* __restrict__ Wf2, __hip_bfloat16* __restrict__ Wf3) {
    const float* W = blockIdx.x ? W3 : W2;
    __hip_bfloat16* Wf = blockIdx.x ? Wf3 : Wf2;
    int t = threadIdx.x;           // 0..511
    int c = t >> 6, l = t & 63;
    int jt = c >> 1, half = c & 1, nn = l & 15, q = l >> 4;
    #pragma unroll
    for (int j = 0; j < 8; j++) {
        int k = half * 32 + q * 8 + j;
        Wf[t * 8 + j] = __float2bfloat16(W[k * 64 + jt * 16 + nn]);
    }
}

// ---------- MFMA linear: out = act(in @ W + b); wave = 16 nodes ----------
template <int RELU>
__global__ void k_linM(const __hip_bfloat16* __restrict__ in,
                       const __hip_bfloat16* __restrict__ Wf,
                       const float* __restrict__ b,
                       __hip_bfloat16* __restrict__ out16, int n) {
    int wave = threadIdx.x >> 6, lane = threadIdx.x & 63;
    int nb = (blockIdx.x * (blockDim.x >> 6) + wave) * 16;
    if (nb >= n) return;
    int m = lane & 15, q = lane >> 4;
    int arow = nb + m; if (arow >= n) arow = n - 1;
    short8 a0 = *reinterpret_cast<const short8*>(in + (size_t)arow * 64 + q * 8);
    short8 a1 = *reinterpret_cast<const short8*>(in + (size_t)arow * 64 + 32 + q * 8);
    #pragma unroll
    for (int jt = 0; jt < 4; jt++) {
        short8 bf0 = *reinterpret_cast<const short8*>(Wf + ((size_t)(jt * 2 + 0) * 64 + lane) * 8);
        short8 bf1 = *reinterpret_cast<const short8*>(Wf + ((size_t)(jt * 2 + 1) * 64 + lane) * 8);
        float4v d = {0.0f, 0.0f, 0.0f, 0.0f};
        d = __builtin_amdgcn_mfma_f32_16x16x32_bf16(a0, bf0, d, 0, 0, 0);
        d = __builtin_amdgcn_mfma_f32_16x16x32_bf16(a1, bf1, d, 0, 0, 0);
        float bias = b[jt * 16 + m];           // C/D col = lane&15
        #pragma unroll
        for (int r = 0; r < 4; r++) {
            int row = q * 4 + r;               // C/D row = quad*4 + reg
            int node = nb + row;
            if (node < n) {
                float v = d[r] + bias;
                if (RELU) v = fmaxf(v, 0.0f);
                out16[(size_t)node * 64 + jt * 16 + m] = __float2bfloat16(v);
            }
        }
    }
}

// ---------- node-parallel pool ----------
__global__ void k_pool_par(const __hip_bfloat16* __restrict__ h,
                           const int* __restrict__ batch,
                           float* __restrict__ sums, int n) {
    int base = blockIdx.x * 128;
    int lim = base + 128; if (lim > n) lim = n;
    int j = threadIdx.x & 63, r = threadIdx.x >> 6;
    float acc = 0.0f; int gcur = -1;
    for (int i = base + r; i < lim; i += 4) {
        int g = batch[i];
        if (g != gcur) {
            if (gcur >= 0) atomicAdd(&sums[gcur * 64 + j], acc);
            acc = 0.0f; gcur = g;
        }
        acc += bf2f(h[(size_t)i * 64 + j]);
    }
    if (gcur >= 0) atomicAdd(&sums[gcur * 64 + j], acc);
}

// ---------- head ----------
__device__ inline int lower_bound_i(const int* __restrict__ a, int n, int key) {
    int lo = 0, hi = n;
    while (lo < hi) {
        int mid = (lo + hi) >> 1;
        if (a[mid] < key) lo = mid + 1; else hi = mid;
    }
    return lo;
}

__global__ void k_head(const float* __restrict__ sums, const int* __restrict__ batch,
                       const float* __restrict__ ge, const float* __restrict__ Wl,
                       const float* __restrict__ bl, float* __restrict__ out,
                       int n, int ng) {
    int g = blockIdx.x * blockDim.x + threadIdx.x;
    if (g < ng) {
        int lo = lower_bound_i(batch, n, g);
        int hi = lower_bound_i(batch, n, g + 1);
        float c = fmaxf((float)(hi - lo), 1.0f);
        float z[5];
        for (int cl = 0; cl < 5; cl++) z[cl] = bl[cl];
        for (int k = 0; k < 64; k++) {
            float p = sums[g * 64 + k] / c;
            for (int cl = 0; cl < 5; cl++) z[cl] += p * Wl[k * 5 + cl];
        }
        for (int k = 0; k < 64; k++) {
            float p = ge[g * 64 + k];
            for (int cl = 0; cl < 5; cl++) z[cl] += p * Wl[(64 + k) * 5 + cl];
        }
        float m = z[0];
        for (int cl = 1; cl < 5; cl++) m = fmaxf(m, z[cl]);
        float s = 0.0f;
        for (int cl = 0; cl < 5; cl++) s += expf(z[cl] - m);
        float lse = m + logf(s);
        for (int cl = 0; cl < 5; cl++) out[g * 5 + cl] = z[cl] - lse;
    }
}

#define ALIGN16(x) (((x) + 15) & ~(size_t)15)

extern "C" void kernel_launch(void* const* d_in, const int* in_sizes, int n_in,
                              void* d_out, int out_size, void* d_ws, size_t ws_size,
                              hipStream_t stream) {
    const float* x    = (const float*)d_in[0];
    const int*   ei   = (const int*)d_in[1];
    const int*   batch= (const int*)d_in[2];
    const float* ge   = (const float*)d_in[3];
    const float* W1   = (const float*)d_in[4];
    const float* b1   = (const float*)d_in[5];
    const float* W2   = (const float*)d_in[6];
    const float* b2   = (const float*)d_in[7];
    const float* W3   = (const float*)d_in[8];
    const float* b3   = (const float*)d_in[9];
    const float* Wl   = (const float*)d_in[10];
    const float* bl   = (const float*)d_in[11];
    float* out = (float*)d_out;

    const int N = in_sizes[0] / 2;   // x is [N,2]
    const int E = in_sizes[1] / 2;   // edge_index is [2,E]
    const int* src = ei;
    const int* dst = ei + E;
    const int NBUK = (N + 255) >> 8;             // 256-node dst buckets

    // ---- workspace layout (segments 16B-aligned) ----
    char* wsb = (char*)d_ws;
    float* dinv   = (float*)wsb;                wsb += ALIGN16((size_t)N * 4);
    float* aggx   = (float*)wsb;                wsb += ALIGN16((size_t)2 * N * 4);
    __hip_bfloat16* h16  = (__hip_bfloat16*)wsb; wsb += ALIGN16((size_t)64 * N * 2);  // h1 -> h2 -> h3
    __hip_bfloat16* agg16= (__hip_bfloat16*)wsb; wsb += ALIGN16((size_t)64 * N * 2);
    float* sums   = (float*)wsb;                wsb += ALIGN16((size_t)NG * 64 * 4);
    __hip_bfloat16* Wf2 = (__hip_bfloat16*)wsb; wsb += ALIGN16((size_t)4096 * 2);
    __hip_bfloat16* Wf3 = (__hip_bfloat16*)wsb; wsb += ALIGN16((size_t)4096 * 2);
    int2*  ebuck  = (int2*)wsb;                 wsb += ALIGN16((size_t)E * 8);
    int2*  csr    = (int2*)wsb;                 wsb += ALIGN16((size_t)E * 8);
    int*   counts = (int*)wsb;                  wsb += ALIGN16((size_t)N * 4);
    int*   row_ptr= (int*)wsb;                  wsb += ALIGN16((size_t)(N + 1) * 4);
    int*   bcur   = (int*)wsb;                  wsb += ALIGN16((size_t)MAXBUK * 4);
    int*   blk_sums=(int*)wsb;                  wsb += 512 * 4;

    const int BS = 256;
    int gN   = (N + BS - 1) / BS;
    int gE   = (E + BS - 1) / BS;
    int gN64 = (N * 64 + BS - 1) / BS;
    int gW   = (N + 3) / 4;                      // k_agg: 4 waves per block
    int gM   = ((N + 15) / 16 + 3) / 4;          // k_linM: 4 waves * 16 nodes
    int gP   = (N + 127) / 128;                  // pool chunks
    int gB   = (E + CHUNKB - 1) / CHUNKB;        // bucket chunks

    // ---- CSR build (clustered-write path) ----
    hipMemsetAsync(counts, 0, (size_t)N * 4, stream);
    hipMemsetAsync(sums, 0, (size_t)NG * 64 * 4, stream);
    k_hist<<<gE, BS, 0, stream>>>(dst, counts, E);
    k_scan1<<<gN, BS, 0, stream>>>(counts, row_ptr, blk_sums, N);
    k_scan2<<<1, 512, 0, stream>>>(blk_sums, gN);
    k_scan3<<<gN, BS, 0, stream>>>(row_ptr, blk_sums, counts, dinv, N, E);
    k_bcur<<<(NBUK + 255) / 256, BS, 0, stream>>>(row_ptr, bcur, NBUK);
    k_bucket<<<gB, BS, 0, stream>>>(src, dst, bcur, ebuck, E, NBUK);
    k_csrfix<<<NBUK, BS, 0, stream>>>(ebuck, row_ptr, dinv, csr, N, NBUK);
    k_prepW<<<2, 512, 0, stream>>>(W2, W3, Wf2, Wf3);

    // ---- layer 1 ----
    k_pull2<<<gN, BS, 0, stream>>>(row_ptr, csr, x, dinv, aggx, N);
    k_lin1<<<gN64, BS, 0, stream>>>(aggx, W1, b1, h16, N);

    // ---- layer 2: agg = A@h1 ; h2 = relu(agg@W2+b2) (overwrites h1) ----
    k_agg<<<gW, BS, 0, stream>>>(row_ptr, csr, h16, dinv, agg16, N);
    k_linM<1><<<gM, BS, 0, stream>>>(agg16, Wf2, b2, h16, N);

    // ---- layer 3: agg = A@h2 ; h3 = agg@W3+b3 -> bf16 (overwrites h2) ----
    k_agg<<<gW, BS, 0, stream>>>(row_ptr, csr, h16, dinv, agg16, N);
    k_linM<0><<<gM, BS, 0, stream>>>(agg16, Wf3, b3, h16, N);

    // ---- pool + head ----
    k_pool_par<<<gP, BS, 0, stream>>>(h16, batch, sums, N);
    k_head<<<1, 128, 0, stream>>>(sums, batch, ge, Wl, bl, out, N, NG);
}

// Round 9
// 276.629 us; speedup vs baseline: 4.3848x; 1.1454x over previous
//
#include <hip/hip_runtime.h>
#include <hip/hip_bf16.h>
#include <math.h>

#define NG 128
#define CHUNKB 4096
#define NBIN 512     // dst buckets of 256 nodes; >= ceil(N/256)

typedef __attribute__((ext_vector_type(8))) short short8;
typedef __attribute__((ext_vector_type(4))) float float4v;

static __device__ __forceinline__ float bf2f(__hip_bfloat16 v) { return __bfloat162float(v); }

// ---------- per-chunk bucket histogram (LDS only, no global atomics) ----------
__global__ void k_bin_hist(const int* __restrict__ dst, int* __restrict__ hist,
                           int e, int nb) {
    __shared__ int h[NBIN];
    for (int i = threadIdx.x; i < NBIN; i += 256) h[i] = 0;
    __syncthreads();
    int base = blockIdx.x * CHUNKB;
    int lim = e - base; if (lim > CHUNKB) lim = CHUNKB;
    for (int k = threadIdx.x; k < lim; k += 256)
        atomicAdd(&h[dst[base + k] >> 8], 1);
    __syncthreads();
    for (int b = threadIdx.x; b < NBIN; b += 256) hist[b * nb + blockIdx.x] = h[b];
}

// ---------- generic exclusive scan (512-thread blocks) ----------
__global__ void __launch_bounds__(512) genscan1(int* __restrict__ a, int* __restrict__ bsums, int n) {
    __shared__ int s[512];
    int tid = threadIdx.x;
    int i = blockIdx.x * 512 + tid;
    int v = (i < n) ? a[i] : 0;
    s[tid] = v;
    __syncthreads();
    for (int d = 1; d < 512; d <<= 1) {
        int t = (tid >= d) ? s[tid - d] : 0;
        __syncthreads();
        s[tid] += t;
        __syncthreads();
    }
    if (i < n) a[i] = s[tid] - v;   // exclusive, in place
    if (tid == 511) bsums[blockIdx.x] = s[511];
}

__global__ void __launch_bounds__(512) genscan2(int* __restrict__ bsums, int nb) {
    __shared__ int s[512];
    int tid = threadIdx.x;
    int v = (tid < nb) ? bsums[tid] : 0;
    s[tid] = v;
    __syncthreads();
    for (int d = 1; d < 512; d <<= 1) {
        int t = (tid >= d) ? s[tid - d] : 0;
        __syncthreads();
        s[tid] += t;
        __syncthreads();
    }
    if (tid < nb) bsums[tid] = s[tid] - v;
}

__global__ void __launch_bounds__(512) genscan3(int* __restrict__ a, const int* __restrict__ bsums, int n) {
    int i = blockIdx.x * 512 + threadIdx.x;
    if (i < n) a[i] += bsums[blockIdx.x];
}

// ---------- LDS-staged bucket scatter (exact offsets, clustered writes) ----------
__global__ void k_bin_scatter(const int* __restrict__ srcs, const int* __restrict__ dsts,
                              const int* __restrict__ offsets, int2* __restrict__ outbuf,
                              int e, int nb) {
    __shared__ int hcnt[NBIN];     // counts -> cursor
    __shared__ int lstart[NBIN];   // local start -> delta
    __shared__ int ss[256];
    __shared__ int2 stage[CHUNKB];
    int tid = threadIdx.x, blk = blockIdx.x, base = blk * CHUNKB;
    int lim = e - base; if (lim > CHUNKB) lim = CHUNKB;
    for (int i = tid; i < NBIN; i += 256) hcnt[i] = 0;
    __syncthreads();
    for (int k = tid; k < lim; k += 256)
        atomicAdd(&hcnt[dsts[base + k] >> 8], 1);
    __syncthreads();
    // exclusive scan of hcnt -> lstart (thread owns 2 consecutive bins)
    int c0 = hcnt[2 * tid], c1 = hcnt[2 * tid + 1];
    int sum = c0 + c1;
    ss[tid] = sum;
    __syncthreads();
    for (int d = 1; d < 256; d <<= 1) {
        int t = (tid >= d) ? ss[tid - d] : 0;
        __syncthreads();
        ss[tid] += t;
        __syncthreads();
    }
    int excl = ss[tid] - sum;
    lstart[2 * tid] = excl;
    lstart[2 * tid + 1] = excl + c0;
    __syncthreads();
    hcnt[2 * tid] = excl;          // cursors
    hcnt[2 * tid + 1] = excl + c0;
    __syncthreads();
    // rank + stage into LDS grouped by bucket
    for (int k = tid; k < lim; k += 256) {
        int2 ed = make_int2(srcs[base + k], dsts[base + k]);
        int p = atomicAdd(&hcnt[ed.y >> 8], 1);
        stage[p] = ed;
    }
    __syncthreads();
    // delta[b] = global run start - local start; then write runs coalesced
    for (int i = tid; i < NBIN; i += 256) lstart[i] = offsets[i * nb + blk] - lstart[i];
    __syncthreads();
    for (int p = tid; p < lim; p += 256) {
        int2 ed = stage[p];
        outbuf[lstart[ed.y >> 8] + p] = ed;
    }
}

// ---------- block per bucket: per-node degree (LDS), row_ptr, dinv ----------
__global__ void k_csrA(const int2* __restrict__ ebuck, const int* __restrict__ offsets,
                       int* __restrict__ row_ptr, float* __restrict__ dinv,
                       int n, int nb, int nbuk, int e_total) {
    __shared__ int lcnt[256];
    __shared__ int ssc[256];
    int b = blockIdx.x, tid = threadIdx.x, n0 = b << 8;
    lcnt[tid] = 0;
    __syncthreads();
    int e0 = offsets[b * nb];
    int e1 = offsets[(b + 1) * nb];   // valid: bucket nbuk..NBIN-1 are empty
    for (int i = e0 + tid; i < e1; i += 256)
        atomicAdd(&lcnt[ebuck[i].y - n0], 1);
    __syncthreads();
    int v = lcnt[tid];
    ssc[tid] = v;
    __syncthreads();
    for (int d = 1; d < 256; d <<= 1) {
        int t = (tid >= d) ? ssc[tid - d] : 0;
        __syncthreads();
        ssc[tid] += t;
        __syncthreads();
    }
    int node = n0 + tid;
    if (node < n) {
        row_ptr[node] = e0 + ssc[tid] - v;   // exclusive
        dinv[node] = rsqrtf((float)v + 1.0f);
        if (node == n - 1) row_ptr[n] = e_total;
    }
}

// ---------- block per bucket: place edges at exact CSR pos, precompute w ----------
__global__ void k_csrB(const int2* __restrict__ ebuck, const int* __restrict__ offsets,
                       const int* __restrict__ row_ptr, const float* __restrict__ dinv,
                       int2* __restrict__ csr, int nb) {
    __shared__ int lcur[256];
    int b = blockIdx.x, tid = threadIdx.x, n0 = b << 8;
    lcur[tid] = 0;
    __syncthreads();
    int e0 = offsets[b * nb];
    int e1 = offsets[(b + 1) * nb];
    for (int i = e0 + tid; i < e1; i += 256) {
        int2 ed = ebuck[i];
        int r = atomicAdd(&lcur[ed.y - n0], 1);
        int pos = row_ptr[ed.y] + r;
        float w = dinv[ed.x] * dinv[ed.y];
        csr[pos] = make_int2(ed.x, __float_as_int(w));
    }
}

// ---------- layer-1 pull on raw 2-feature x ----------
__global__ void k_pull2(const int* __restrict__ row_ptr, const int2* __restrict__ edges,
                        const float* __restrict__ x, const float* __restrict__ dinv,
                        float* __restrict__ out, int n) {
    int i = blockIdx.x * blockDim.x + threadIdx.x;
    if (i < n) {
        const float2* x2 = (const float2*)x;
        float dd = dinv[i], d2 = dd * dd;
        float2 xi = x2[i];
        float a0 = d2 * xi.x, a1 = d2 * xi.y;
        int lo = row_ptr[i], hi = row_ptr[i + 1];
        int k = lo;
        for (; k + 4 <= hi; k += 4) {
            int2 e0 = edges[k], e1 = edges[k + 1], e2 = edges[k + 2], e3 = edges[k + 3];
            float2 v0 = x2[e0.x], v1 = x2[e1.x], v2 = x2[e2.x], v3 = x2[e3.x];
            a0 += __int_as_float(e0.y) * v0.x; a1 += __int_as_float(e0.y) * v0.y;
            a0 += __int_as_float(e1.y) * v1.x; a1 += __int_as_float(e1.y) * v1.y;
            a0 += __int_as_float(e2.y) * v2.x; a1 += __int_as_float(e2.y) * v2.y;
            a0 += __int_as_float(e3.y) * v3.x; a1 += __int_as_float(e3.y) * v3.y;
        }
        for (; k < hi; k++) {
            int2 e = edges[k];
            float2 v = x2[e.x];
            a0 += __int_as_float(e.y) * v.x;
            a1 += __int_as_float(e.y) * v.y;
        }
        out[2 * i] = a0;
        out[2 * i + 1] = a1;
    }
}

// h1 = relu(aggx @ W1 + b1) -> bf16
__global__ void k_lin1(const float* __restrict__ aggx, const float* __restrict__ W1,
                       const float* __restrict__ b1, __hip_bfloat16* __restrict__ h, int n) {
    int t = blockIdx.x * blockDim.x + threadIdx.x;
    if (t < n * 64) {
        int i = t >> 6, j = t & 63;
        float v = aggx[2 * i] * W1[j] + aggx[2 * i + 1] * W1[64 + j] + b1[j];
        h[t] = __float2bfloat16(fmaxf(v, 0.0f));
    }
}

// ---------- width-64 pull aggregation (bf16 gather, fp32 acc, 8-wide ILP) ----------
__global__ void k_agg(const int* __restrict__ row_ptr, const int2* __restrict__ edges,
                      const __hip_bfloat16* __restrict__ h, const float* __restrict__ dinv,
                      __hip_bfloat16* __restrict__ out, int n) {
    int node = blockIdx.x * (blockDim.x >> 6) + (threadIdx.x >> 6);
    int lane = threadIdx.x & 63;
    if (node >= n) return;
    float dn = dinv[node];
    float acc = dn * dn * bf2f(h[(size_t)node * 64 + lane]);
    int lo = row_ptr[node], hi = row_ptr[node + 1];
    for (int base = lo; base < hi; base += 64) {
        int take = hi - base; if (take > 64) take = 64;
        int take8 = (take + 7) & ~7;     // pad lanes carry w=0, s=0
        int sl = 0; float wl = 0.0f;
        if (base + lane < hi) {
            int2 e = edges[base + lane];  // coalesced
            sl = e.x; wl = __int_as_float(e.y);
        }
        for (int k = 0; k < take8; k += 8) {
            int   s0 = __shfl(sl, k),     s1 = __shfl(sl, k + 1);
            int   s2 = __shfl(sl, k + 2), s3 = __shfl(sl, k + 3);
            int   s4 = __shfl(sl, k + 4), s5 = __shfl(sl, k + 5);
            int   s6 = __shfl(sl, k + 6), s7 = __shfl(sl, k + 7);
            float w0 = __shfl(wl, k),     w1 = __shfl(wl, k + 1);
            float w2 = __shfl(wl, k + 2), w3 = __shfl(wl, k + 3);
            float w4 = __shfl(wl, k + 4), w5 = __shfl(wl, k + 5);
            float w6 = __shfl(wl, k + 6), w7 = __shfl(wl, k + 7);
            float v0 = bf2f(h[(size_t)s0 * 64 + lane]);
            float v1 = bf2f(h[(size_t)s1 * 64 + lane]);
            float v2 = bf2f(h[(size_t)s2 * 64 + lane]);
            float v3 = bf2f(h[(size_t)s3 * 64 + lane]);
            float v4 = bf2f(h[(size_t)s4 * 64 + lane]);
            float v5 = bf2f(h[(size_t)s5 * 64 + lane]);
            float v6 = bf2f(h[(size_t)s6 * 64 + lane]);
            float v7 = bf2f(h[(size_t)s7 * 64 + lane]);
            acc += w0 * v0; acc += w1 * v1; acc += w2 * v2; acc += w3 * v3;
            acc += w4 * v4; acc += w5 * v5; acc += w6 * v6; acc += w7 * v7;
        }
    }
    out[(size_t)node * 64 + lane] = __float2bfloat16(acc);
}

// ---------- pack W (64x64 fp32) into MFMA B-fragment order, bf16 ----------
__global__ void k_prepW(const float* __restrict__ W2, const float* __restrict__ W3,
                        __hip_bfloat16* __restrict__ Wf2, __hip_bfloat16* __restrict__ Wf3) {
    const float* W = blockIdx.x ? W3 : W2;
    __hip_bfloat16* Wf = blockIdx.x ? Wf3 : Wf2;
    int t = threadIdx.x;           // 0..511
    int c = t >> 6, l = t & 63;
    int jt = c >> 1, half = c & 1, nn = l & 15, q = l >> 4;
    #pragma unroll
    for (int j = 0; j < 8; j++) {
        int k = half * 32 + q * 8 + j;
        Wf[t * 8 + j] = __float2bfloat16(W[k * 64 + jt * 16 + nn]);
    }
}

// ---------- MFMA linear: out = act(in @ W + b); wave = 16 nodes ----------
template <int RELU>
__global__ void k_linM(const __hip_bfloat16* __restrict__ in,
                       const __hip_bfloat16* __restrict__ Wf,
                       const float* __restrict__ b,
                       __hip_bfloat16* __restrict__ out16, int n) {
    int wave = threadIdx.x >> 6, lane = threadIdx.x & 63;
    int nb = (blockIdx.x * (blockDim.x >> 6) + wave) * 16;
    if (nb >= n) return;
    int m = lane & 15, q = lane >> 4;
    int arow = nb + m; if (arow >= n) arow = n - 1;
    short8 a0 = *reinterpret_cast<const short8*>(in + (size_t)arow * 64 + q * 8);
    short8 a1 = *reinterpret_cast<const short8*>(in + (size_t)arow * 64 + 32 + q * 8);
    #pragma unroll
    for (int jt = 0; jt < 4; jt++) {
        short8 bf0 = *reinterpret_cast<const short8*>(Wf + ((size_t)(jt * 2 + 0) * 64 + lane) * 8);
        short8 bf1 = *reinterpret_cast<const short8*>(Wf + ((size_t)(jt * 2 + 1) * 64 + lane) * 8);
        float4v d = {0.0f, 0.0f, 0.0f, 0.0f};
        d = __builtin_amdgcn_mfma_f32_16x16x32_bf16(a0, bf0, d, 0, 0, 0);
        d = __builtin_amdgcn_mfma_f32_16x16x32_bf16(a1, bf1, d, 0, 0, 0);
        float bias = b[jt * 16 + m];           // C/D col = lane&15
        #pragma unroll
        for (int r = 0; r < 4; r++) {
            int row = q * 4 + r;               // C/D row = quad*4 + reg
            int node = nb + row;
            if (node < n) {
                float v = d[r] + bias;
                if (RELU) v = fmaxf(v, 0.0f);
                out16[(size_t)node * 64 + jt * 16 + m] = __float2bfloat16(v);
            }
        }
    }
}

// ---------- node-parallel pool ----------
__global__ void k_pool_par(const __hip_bfloat16* __restrict__ h,
                           const int* __restrict__ batch,
                           float* __restrict__ sums, int n) {
    int base = blockIdx.x * 128;
    int lim = base + 128; if (lim > n) lim = n;
    int j = threadIdx.x & 63, r = threadIdx.x >> 6;
    float acc = 0.0f; int gcur = -1;
    for (int i = base + r; i < lim; i += 4) {
        int g = batch[i];
        if (g != gcur) {
            if (gcur >= 0) atomicAdd(&sums[gcur * 64 + j], acc);
            acc = 0.0f; gcur = g;
        }
        acc += bf2f(h[(size_t)i * 64 + j]);
    }
    if (gcur >= 0) atomicAdd(&sums[gcur * 64 + j], acc);
}

// ---------- head ----------
__device__ inline int lower_bound_i(const int* __restrict__ a, int n, int key) {
    int lo = 0, hi = n;
    while (lo < hi) {
        int mid = (lo + hi) >> 1;
        if (a[mid] < key) lo = mid + 1; else hi = mid;
    }
    return lo;
}

__global__ void k_head(const float* __restrict__ sums, const int* __restrict__ batch,
                       const float* __restrict__ ge, const float* __restrict__ Wl,
                       const float* __restrict__ bl, float* __restrict__ out,
                       int n, int ng) {
    int g = blockIdx.x * blockDim.x + threadIdx.x;
    if (g < ng) {
        int lo = lower_bound_i(batch, n, g);
        int hi = lower_bound_i(batch, n, g + 1);
        float c = fmaxf((float)(hi - lo), 1.0f);
        float z[5];
        for (int cl = 0; cl < 5; cl++) z[cl] = bl[cl];
        for (int k = 0; k < 64; k++) {
            float p = sums[g * 64 + k] / c;
            for (int cl = 0; cl < 5; cl++) z[cl] += p * Wl[k * 5 + cl];
        }
        for (int k = 0; k < 64; k++) {
            float p = ge[g * 64 + k];
            for (int cl = 0; cl < 5; cl++) z[cl] += p * Wl[(64 + k) * 5 + cl];
        }
        float m = z[0];
        for (int cl = 1; cl < 5; cl++) m = fmaxf(m, z[cl]);
        float s = 0.0f;
        for (int cl = 0; cl < 5; cl++) s += expf(z[cl] - m);
        float lse = m + logf(s);
        for (int cl = 0; cl < 5; cl++) out[g * 5 + cl] = z[cl] - lse;
    }
}

#define ALIGN16(x) (((x) + 15) & ~(size_t)15)

extern "C" void kernel_launch(void* const* d_in, const int* in_sizes, int n_in,
                              void* d_out, int out_size, void* d_ws, size_t ws_size,
                              hipStream_t stream) {
    const float* x    = (const float*)d_in[0];
    const int*   ei   = (const int*)d_in[1];
    const int*   batch= (const int*)d_in[2];
    const float* ge   = (const float*)d_in[3];
    const float* W1   = (const float*)d_in[4];
    const float* b1   = (const float*)d_in[5];
    const float* W2   = (const float*)d_in[6];
    const float* b2   = (const float*)d_in[7];
    const float* W3   = (const float*)d_in[8];
    const float* b3   = (const float*)d_in[9];
    const float* Wl   = (const float*)d_in[10];
    const float* bl   = (const float*)d_in[11];
    float* out = (float*)d_out;

    const int N = in_sizes[0] / 2;   // x is [N,2]
    const int E = in_sizes[1] / 2;   // edge_index is [2,E]
    const int* src = ei;
    const int* dst = ei + E;
    const int NBUK = (N + 255) >> 8;             // actual dst buckets (<= NBIN)
    const int nbC  = (E + CHUNKB - 1) / CHUNKB;  // sort chunks

    // ---- workspace layout (segments 16B-aligned) ----
    char* wsb = (char*)d_ws;
    float* dinv   = (float*)wsb;                wsb += ALIGN16((size_t)N * 4);
    float* aggx   = (float*)wsb;                wsb += ALIGN16((size_t)2 * N * 4);
    __hip_bfloat16* h16  = (__hip_bfloat16*)wsb; wsb += ALIGN16((size_t)64 * N * 2);  // h1 -> h2 -> h3
    __hip_bfloat16* agg16= (__hip_bfloat16*)wsb; wsb += ALIGN16((size_t)64 * N * 2);
    float* sums   = (float*)wsb;                wsb += ALIGN16((size_t)NG * 64 * 4);
    __hip_bfloat16* Wf2 = (__hip_bfloat16*)wsb; wsb += ALIGN16((size_t)4096 * 2);
    __hip_bfloat16* Wf3 = (__hip_bfloat16*)wsb; wsb += ALIGN16((size_t)4096 * 2);
    int2*  ebuck  = (int2*)wsb;                 wsb += ALIGN16((size_t)E * 8);
    int2*  csr    = (int2*)wsb;                 wsb += ALIGN16((size_t)E * 8);
    int*   row_ptr= (int*)wsb;                  wsb += ALIGN16((size_t)(N + 1) * 4);
    int*   hist   = (int*)wsb;                  wsb += ALIGN16((size_t)NBIN * nbC * 4);
    int*   bsums  = (int*)wsb;                  wsb += 512 * 4;

    const int BS = 256;
    int gN   = (N + BS - 1) / BS;
    int gN64 = (N * 64 + BS - 1) / BS;
    int gW   = (N + 3) / 4;                      // k_agg: 4 waves per block
    int gM   = ((N + 15) / 16 + 3) / 4;          // k_linM: 4 waves * 16 nodes
    int gP   = (N + 127) / 128;                  // pool chunks
    int nH   = NBIN * nbC;
    int gH   = (nH + 511) / 512;                 // <= 512 for genscan2

    // ---- CSR build: single-pass bucket sort, all histograms in LDS ----
    hipMemsetAsync(sums, 0, (size_t)NG * 64 * 4, stream);
    k_bin_hist<<<nbC, BS, 0, stream>>>(dst, hist, E, nbC);
    genscan1<<<gH, 512, 0, stream>>>(hist, bsums, nH);
    genscan2<<<1, 512, 0, stream>>>(bsums, gH);
    genscan3<<<gH, 512, 0, stream>>>(hist, bsums, nH);
    k_bin_scatter<<<nbC, BS, 0, stream>>>(src, dst, hist, ebuck, E, nbC);
    k_csrA<<<NBUK, BS, 0, stream>>>(ebuck, hist, row_ptr, dinv, N, nbC, NBUK, E);
    k_csrB<<<NBUK, BS, 0, stream>>>(ebuck, hist, row_ptr, dinv, csr, nbC);
    k_prepW<<<2, 512, 0, stream>>>(W2, W3, Wf2, Wf3);

    // ---- layer 1 ----
    k_pull2<<<gN, BS, 0, stream>>>(row_ptr, csr, x, dinv, aggx, N);
    k_lin1<<<gN64, BS, 0, stream>>>(aggx, W1, b1, h16, N);

    // ---- layer 2: agg = A@h1 ; h2 = relu(agg@W2+b2) (overwrites h1) ----
    k_agg<<<gW, BS, 0, stream>>>(row_ptr, csr, h16, dinv, agg16, N);
    k_linM<1><<<gM, BS, 0, stream>>>(agg16, Wf2, b2, h16, N);

    // ---- layer 3: agg = A@h2 ; h3 = agg@W3+b3 -> bf16 (overwrites h2) ----
    k_agg<<<gW, BS, 0, stream>>>(row_ptr, csr, h16, dinv, agg16, N);
    k_linM<0><<<gM, BS, 0, stream>>>(agg16, Wf3, b3, h16, N);

    // ---- pool + head ----
    k_pool_par<<<gP, BS, 0, stream>>>(h16, batch, sums, N);
    k_head<<<1, 128, 0, stream>>>(sums, batch, ge, Wl, bl, out, N, NG);
}

// Round 10
// 266.408 us; speedup vs baseline: 4.5530x; 1.0384x over previous
//
#include <hip/hip_runtime.h>
#include <hip/hip_bf16.h>
#include <math.h>

#define NG 128
#define CHUNKB 4096
#define NBIN 512     // dst buckets of 256 nodes; >= ceil(N/256)

typedef __attribute__((ext_vector_type(8))) short short8;
typedef __attribute__((ext_vector_type(4))) float float4v;

static __device__ __forceinline__ float bf2f(__hip_bfloat16 v) { return __bfloat162float(v); }

// ---------- per-chunk bucket histogram (LDS only, no global atomics) ----------
__global__ void k_bin_hist(const int* __restrict__ dst, int* __restrict__ hist,
                           int e, int nb) {
    __shared__ int h[NBIN];
    for (int i = threadIdx.x; i < NBIN; i += 256) h[i] = 0;
    __syncthreads();
    int base = blockIdx.x * CHUNKB;
    int lim = e - base; if (lim > CHUNKB) lim = CHUNKB;
    for (int k = threadIdx.x; k < lim; k += 256)
        atomicAdd(&h[dst[base + k] >> 8], 1);
    __syncthreads();
    for (int b = threadIdx.x; b < NBIN; b += 256) hist[b * nb + blockIdx.x] = h[b];
}

// ---------- generic exclusive scan (512-thread blocks) ----------
__global__ void __launch_bounds__(512) genscan1(int* __restrict__ a, int* __restrict__ bsums, int n) {
    __shared__ int s[512];
    int tid = threadIdx.x;
    int i = blockIdx.x * 512 + tid;
    int v = (i < n) ? a[i] : 0;
    s[tid] = v;
    __syncthreads();
    for (int d = 1; d < 512; d <<= 1) {
        int t = (tid >= d) ? s[tid - d] : 0;
        __syncthreads();
        s[tid] += t;
        __syncthreads();
    }
    if (i < n) a[i] = s[tid] - v;   // exclusive, in place
    if (tid == 511) bsums[blockIdx.x] = s[511];
}

__global__ void __launch_bounds__(512) genscan2(int* __restrict__ bsums, int nb) {
    __shared__ int s[512];
    int tid = threadIdx.x;
    int v = (tid < nb) ? bsums[tid] : 0;
    s[tid] = v;
    __syncthreads();
    for (int d = 1; d < 512; d <<= 1) {
        int t = (tid >= d) ? s[tid - d] : 0;
        __syncthreads();
        s[tid] += t;
        __syncthreads();
    }
    if (tid < nb) bsums[tid] = s[tid] - v;
}

__global__ void __launch_bounds__(512) genscan3(int* __restrict__ a, const int* __restrict__ bsums, int n) {
    int i = blockIdx.x * 512 + threadIdx.x;
    if (i < n) a[i] += bsums[blockIdx.x];
}

// ---------- LDS-staged bucket scatter (exact offsets, clustered writes) ----------
__global__ void k_bin_scatter(const int* __restrict__ srcs, const int* __restrict__ dsts,
                              const int* __restrict__ offsets, int2* __restrict__ outbuf,
                              int e, int nb) {
    __shared__ int hcnt[NBIN];     // counts -> cursor
    __shared__ int lstart[NBIN];   // local start -> delta
    __shared__ int ss[256];
    __shared__ int2 stage[CHUNKB];
    int tid = threadIdx.x, blk = blockIdx.x, base = blk * CHUNKB;
    int lim = e - base; if (lim > CHUNKB) lim = CHUNKB;
    for (int i = tid; i < NBIN; i += 256) hcnt[i] = 0;
    __syncthreads();
    for (int k = tid; k < lim; k += 256)
        atomicAdd(&hcnt[dsts[base + k] >> 8], 1);
    __syncthreads();
    int c0 = hcnt[2 * tid], c1 = hcnt[2 * tid + 1];
    int sum = c0 + c1;
    ss[tid] = sum;
    __syncthreads();
    for (int d = 1; d < 256; d <<= 1) {
        int t = (tid >= d) ? ss[tid - d] : 0;
        __syncthreads();
        ss[tid] += t;
        __syncthreads();
    }
    int excl = ss[tid] - sum;
    lstart[2 * tid] = excl;
    lstart[2 * tid + 1] = excl + c0;
    __syncthreads();
    hcnt[2 * tid] = excl;          // cursors
    hcnt[2 * tid + 1] = excl + c0;
    __syncthreads();
    for (int k = tid; k < lim; k += 256) {
        int2 ed = make_int2(srcs[base + k], dsts[base + k]);
        int p = atomicAdd(&hcnt[ed.y >> 8], 1);
        stage[p] = ed;
    }
    __syncthreads();
    for (int i = tid; i < NBIN; i += 256) lstart[i] = offsets[i * nb + blk] - lstart[i];
    __syncthreads();
    for (int p = tid; p < lim; p += 256) {
        int2 ed = stage[p];
        outbuf[lstart[ed.y >> 8] + p] = ed;
    }
}

// ---------- block per bucket: per-node degree (LDS), row_ptr, dinv ----------
__global__ void k_csrA(const int2* __restrict__ ebuck, const int* __restrict__ offsets,
                       int* __restrict__ row_ptr, float* __restrict__ dinv,
                       int n, int nb, int nbuk, int e_total) {
    __shared__ int lcnt[256];
    __shared__ int ssc[256];
    int b = blockIdx.x, tid = threadIdx.x, n0 = b << 8;
    lcnt[tid] = 0;
    __syncthreads();
    int e0 = offsets[b * nb];
    int e1 = offsets[(b + 1) * nb];
    for (int i = e0 + tid; i < e1; i += 256)
        atomicAdd(&lcnt[ebuck[i].y - n0], 1);
    __syncthreads();
    int v = lcnt[tid];
    ssc[tid] = v;
    __syncthreads();
    for (int d = 1; d < 256; d <<= 1) {
        int t = (tid >= d) ? ssc[tid - d] : 0;
        __syncthreads();
        ssc[tid] += t;
        __syncthreads();
    }
    int node = n0 + tid;
    if (node < n) {
        row_ptr[node] = e0 + ssc[tid] - v;   // exclusive
        dinv[node] = rsqrtf((float)v + 1.0f);
        if (node == n - 1) row_ptr[n] = e_total;
    }
}

// ---------- block per bucket: place edges at exact CSR pos, precompute w ----------
__global__ void k_csrB(const int2* __restrict__ ebuck, const int* __restrict__ offsets,
                       const int* __restrict__ row_ptr, const float* __restrict__ dinv,
                       int2* __restrict__ csr, int nb) {
    __shared__ int lcur[256];
    int b = blockIdx.x, tid = threadIdx.x, n0 = b << 8;
    lcur[tid] = 0;
    __syncthreads();
    int e0 = offsets[b * nb];
    int e1 = offsets[(b + 1) * nb];
    for (int i = e0 + tid; i < e1; i += 256) {
        int2 ed = ebuck[i];
        int r = atomicAdd(&lcur[ed.y - n0], 1);
        int pos = row_ptr[ed.y] + r;
        float w = dinv[ed.x] * dinv[ed.y];
        csr[pos] = make_int2(ed.x, __float_as_int(w));
    }
}

// ---------- layer 1 fused: pull on x (2 feats) + lin1 + relu -> h1 bf16 ----------
__global__ void k_layer1(const int* __restrict__ row_ptr, const int2* __restrict__ edges,
                         const float* __restrict__ x, const float* __restrict__ dinv,
                         const float* __restrict__ W1, const float* __restrict__ b1,
                         __hip_bfloat16* __restrict__ h, int n) {
    __shared__ float w1s[128];
    __shared__ float b1s[64];
    if (threadIdx.x < 128) w1s[threadIdx.x] = W1[threadIdx.x];
    if (threadIdx.x < 64) b1s[threadIdx.x] = b1[threadIdx.x];
    __syncthreads();
    int i = blockIdx.x * blockDim.x + threadIdx.x;
    if (i >= n) return;
    const float2* x2 = (const float2*)x;
    float dd = dinv[i], d2 = dd * dd;
    float2 xi = x2[i];
    float a0 = d2 * xi.x, a1 = d2 * xi.y;
    int lo = row_ptr[i], hi = row_ptr[i + 1];
    int k = lo;
    for (; k + 4 <= hi; k += 4) {
        int2 e0 = edges[k], e1 = edges[k + 1], e2 = edges[k + 2], e3 = edges[k + 3];
        float2 v0 = x2[e0.x], v1 = x2[e1.x], v2 = x2[e2.x], v3 = x2[e3.x];
        a0 += __int_as_float(e0.y) * v0.x; a1 += __int_as_float(e0.y) * v0.y;
        a0 += __int_as_float(e1.y) * v1.x; a1 += __int_as_float(e1.y) * v1.y;
        a0 += __int_as_float(e2.y) * v2.x; a1 += __int_as_float(e2.y) * v2.y;
        a0 += __int_as_float(e3.y) * v3.x; a1 += __int_as_float(e3.y) * v3.y;
    }
    for (; k < hi; k++) {
        int2 e = edges[k];
        float2 v = x2[e.x];
        a0 += __int_as_float(e.y) * v.x;
        a1 += __int_as_float(e.y) * v.y;
    }
    // h1 row = relu(a0*W1[0,:] + a1*W1[1,:] + b1), packed 8-at-a-time
    short8* hv = reinterpret_cast<short8*>(h + (size_t)i * 64);
    #pragma unroll
    for (int g = 0; g < 8; g++) {
        short8 pack;
        #pragma unroll
        for (int j = 0; j < 8; j++) {
            int col = g * 8 + j;
            float v = fmaxf(a0 * w1s[col] + a1 * w1s[64 + col] + b1s[col], 0.0f);
            __hip_bfloat16 bv = __float2bfloat16(v);
            pack[j] = *reinterpret_cast<short*>(&bv);
        }
        hv[g] = pack;
    }
}

// ---------- fused agg + MFMA linear: wave = 16 nodes ----------
// Phase 1: gather-accumulate each node's 64-feat row (full wave), park bf16 in
// wave-private LDS tile. Phase 2: MFMA linear on the tile, write layer output.
// No __syncthreads needed: tiles are wave-private.
template <int RELU>
__global__ void __launch_bounds__(256) k_aggLin(const int* __restrict__ row_ptr,
                                                const int2* __restrict__ edges,
                                                const __hip_bfloat16* __restrict__ hin,
                                                const float* __restrict__ dinv,
                                                const __hip_bfloat16* __restrict__ Wf,
                                                const float* __restrict__ b,
                                                __hip_bfloat16* __restrict__ hout, int n) {
    __shared__ __attribute__((aligned(16))) __hip_bfloat16 tile[4][16 * 72]; // stride 72 shorts: 16B-aligned rows
    int wave = threadIdx.x >> 6, lane = threadIdx.x & 63;
    int nb0 = (blockIdx.x * 4 + wave) * 16;
    if (nb0 >= n) return;
    __hip_bfloat16* T = &tile[wave][0];

    for (int nn = 0; nn < 16; nn++) {
        int node = nb0 + nn;
        float acc = 0.0f;
        if (node < n) {
            float dn = dinv[node];
            acc = dn * dn * bf2f(hin[(size_t)node * 64 + lane]);
            int lo = row_ptr[node], hi = row_ptr[node + 1];
            for (int base = lo; base < hi; base += 64) {
                int take = hi - base; if (take > 64) take = 64;
                int take8 = (take + 7) & ~7;     // pad lanes carry w=0, s=0
                int sl = 0; float wl = 0.0f;
                if (base + lane < hi) {
                    int2 e = edges[base + lane];  // coalesced
                    sl = e.x; wl = __int_as_float(e.y);
                }
                for (int k = 0; k < take8; k += 8) {
                    int   s0 = __shfl(sl, k),     s1 = __shfl(sl, k + 1);
                    int   s2 = __shfl(sl, k + 2), s3 = __shfl(sl, k + 3);
                    int   s4 = __shfl(sl, k + 4), s5 = __shfl(sl, k + 5);
                    int   s6 = __shfl(sl, k + 6), s7 = __shfl(sl, k + 7);
                    float w0 = __shfl(wl, k),     w1 = __shfl(wl, k + 1);
                    float w2 = __shfl(wl, k + 2), w3 = __shfl(wl, k + 3);
                    float w4 = __shfl(wl, k + 4), w5 = __shfl(wl, k + 5);
                    float w6 = __shfl(wl, k + 6), w7 = __shfl(wl, k + 7);
                    float v0 = bf2f(hin[(size_t)s0 * 64 + lane]);
                    float v1 = bf2f(hin[(size_t)s1 * 64 + lane]);
                    float v2 = bf2f(hin[(size_t)s2 * 64 + lane]);
                    float v3 = bf2f(hin[(size_t)s3 * 64 + lane]);
                    float v4 = bf2f(hin[(size_t)s4 * 64 + lane]);
                    float v5 = bf2f(hin[(size_t)s5 * 64 + lane]);
                    float v6 = bf2f(hin[(size_t)s6 * 64 + lane]);
                    float v7 = bf2f(hin[(size_t)s7 * 64 + lane]);
                    acc += w0 * v0; acc += w1 * v1; acc += w2 * v2; acc += w3 * v3;
                    acc += w4 * v4; acc += w5 * v5; acc += w6 * v6; acc += w7 * v7;
                }
            }
        }
        T[nn * 72 + lane] = __float2bfloat16(acc);
    }

    // MFMA phase on the wave's 16x64 tile
    int m = lane & 15, q = lane >> 4;
    short8 a0 = *reinterpret_cast<const short8*>(&T[m * 72 + q * 8]);
    short8 a1 = *reinterpret_cast<const short8*>(&T[m * 72 + 32 + q * 8]);
    #pragma unroll
    for (int jt = 0; jt < 4; jt++) {
        short8 bf0 = *reinterpret_cast<const short8*>(Wf + ((size_t)(jt * 2 + 0) * 64 + lane) * 8);
        short8 bf1 = *reinterpret_cast<const short8*>(Wf + ((size_t)(jt * 2 + 1) * 64 + lane) * 8);
        float4v d = {0.0f, 0.0f, 0.0f, 0.0f};
        d = __builtin_amdgcn_mfma_f32_16x16x32_bf16(a0, bf0, d, 0, 0, 0);
        d = __builtin_amdgcn_mfma_f32_16x16x32_bf16(a1, bf1, d, 0, 0, 0);
        float bias = b[jt * 16 + m];           // C/D col = lane&15
        #pragma unroll
        for (int r = 0; r < 4; r++) {
            int row = q * 4 + r;               // C/D row = quad*4 + reg
            int node = nb0 + row;
            if (node < n) {
                float v = d[r] + bias;
                if (RELU) v = fmaxf(v, 0.0f);
                hout[(size_t)node * 64 + jt * 16 + m] = __float2bfloat16(v);
            }
        }
    }
}

// ---------- pack W (64x64 fp32) into MFMA B-fragment order, bf16 ----------
__global__ void k_prepW(const float* __restrict__ W2, const float* __restrict__ W3,
                        __hip_bfloat16* __restrict__ Wf2, __hip_bfloat16* __restrict__ Wf3) {
    const float* W = blockIdx.x ? W3 : W2;
    __hip_bfloat16* Wf = blockIdx.x ? Wf3 : Wf2;
    int t = threadIdx.x;           // 0..511
    int c = t >> 6, l = t & 63;
    int jt = c >> 1, half = c & 1, nn = l & 15, q = l >> 4;
    #pragma unroll
    for (int j = 0; j < 8; j++) {
        int k = half * 32 + q * 8 + j;
        Wf[t * 8 + j] = __float2bfloat16(W[k * 64 + jt * 16 + nn]);
    }
}

// ---------- node-parallel pool ----------
__global__ void k_pool_par(const __hip_bfloat16* __restrict__ h,
                           const int* __restrict__ batch,
                           float* __restrict__ sums, int n) {
    int base = blockIdx.x * 128;
    int lim = base + 128; if (lim > n) lim = n;
    int j = threadIdx.x & 63, r = threadIdx.x >> 6;
    float acc = 0.0f; int gcur = -1;
    for (int i = base + r; i < lim; i += 4) {
        int g = batch[i];
        if (g != gcur) {
            if (gcur >= 0) atomicAdd(&sums[gcur * 64 + j], acc);
            acc = 0.0f; gcur = g;
        }
        acc += bf2f(h[(size_t)i * 64 + j]);
    }
    if (gcur >= 0) atomicAdd(&sums[gcur * 64 + j], acc);
}

// ---------- head ----------
__device__ inline int lower_bound_i(const int* __restrict__ a, int n, int key) {
    int lo = 0, hi = n;
    while (lo < hi) {
        int mid = (lo + hi) >> 1;
        if (a[mid] < key) lo = mid + 1; else hi = mid;
    }
    return lo;
}

__global__ void k_head(const float* __restrict__ sums, const int* __restrict__ batch,
                       const float* __restrict__ ge, const float* __restrict__ Wl,
                       const float* __restrict__ bl, float* __restrict__ out,
                       int n, int ng) {
    int g = blockIdx.x * blockDim.x + threadIdx.x;
    if (g < ng) {
        int lo = lower_bound_i(batch, n, g);
        int hi = lower_bound_i(batch, n, g + 1);
        float c = fmaxf((float)(hi - lo), 1.0f);
        float z[5];
        for (int cl = 0; cl < 5; cl++) z[cl] = bl[cl];
        for (int k = 0; k < 64; k++) {
            float p = sums[g * 64 + k] / c;
            for (int cl = 0; cl < 5; cl++) z[cl] += p * Wl[k * 5 + cl];
        }
        for (int k = 0; k < 64; k++) {
            float p = ge[g * 64 + k];
            for (int cl = 0; cl < 5; cl++) z[cl] += p * Wl[(64 + k) * 5 + cl];
        }
        float m = z[0];
        for (int cl = 1; cl < 5; cl++) m = fmaxf(m, z[cl]);
        float s = 0.0f;
        for (int cl = 0; cl < 5; cl++) s += expf(z[cl] - m);
        float lse = m + logf(s);
        for (int cl = 0; cl < 5; cl++) out[g * 5 + cl] = z[cl] - lse;
    }
}

#define ALIGN16(x) (((x) + 15) & ~(size_t)15)

extern "C" void kernel_launch(void* const* d_in, const int* in_sizes, int n_in,
                              void* d_out, int out_size, void* d_ws, size_t ws_size,
                              hipStream_t stream) {
    const float* x    = (const float*)d_in[0];
    const int*   ei   = (const int*)d_in[1];
    const int*   batch= (const int*)d_in[2];
    const float* ge   = (const float*)d_in[3];
    const float* W1   = (const float*)d_in[4];
    const float* b1   = (const float*)d_in[5];
    const float* W2   = (const float*)d_in[6];
    const float* b2   = (const float*)d_in[7];
    const float* W3   = (const float*)d_in[8];
    const float* b3   = (const float*)d_in[9];
    const float* Wl   = (const float*)d_in[10];
    const float* bl   = (const float*)d_in[11];
    float* out = (float*)d_out;

    const int N = in_sizes[0] / 2;   // x is [N,2]
    const int E = in_sizes[1] / 2;   // edge_index is [2,E]
    const int* src = ei;
    const int* dst = ei + E;
    const int NBUK = (N + 255) >> 8;             // actual dst buckets (<= NBIN)
    const int nbC  = (E + CHUNKB - 1) / CHUNKB;  // sort chunks

    // ---- workspace layout (segments 16B-aligned) ----
    char* wsb = (char*)d_ws;
    float* dinv   = (float*)wsb;                wsb += ALIGN16((size_t)N * 4);
    __hip_bfloat16* h16 = (__hip_bfloat16*)wsb;  wsb += ALIGN16((size_t)64 * N * 2);  // h1 / h3
    __hip_bfloat16* buf2= (__hip_bfloat16*)wsb;  wsb += ALIGN16((size_t)64 * N * 2);  // h2
    float* sums   = (float*)wsb;                wsb += ALIGN16((size_t)NG * 64 * 4);
    __hip_bfloat16* Wf2 = (__hip_bfloat16*)wsb; wsb += ALIGN16((size_t)4096 * 2);
    __hip_bfloat16* Wf3 = (__hip_bfloat16*)wsb; wsb += ALIGN16((size_t)4096 * 2);
    int2*  ebuck  = (int2*)wsb;                 wsb += ALIGN16((size_t)E * 8);
    int2*  csr    = (int2*)wsb;                 wsb += ALIGN16((size_t)E * 8);
    int*   row_ptr= (int*)wsb;                  wsb += ALIGN16((size_t)(N + 1) * 4);
    int*   hist   = (int*)wsb;                  wsb += ALIGN16((size_t)NBIN * nbC * 4);
    int*   bsums  = (int*)wsb;                  wsb += 512 * 4;

    const int BS = 256;
    int gN   = (N + BS - 1) / BS;
    int gF   = ((N + 15) / 16 + 3) / 4;          // k_aggLin: 4 waves * 16 nodes
    int gP   = (N + 127) / 128;                  // pool chunks
    int nH   = NBIN * nbC;
    int gH   = (nH + 511) / 512;                 // <= 512 for genscan2

    // ---- CSR build: single-pass bucket sort, all histograms in LDS ----
    hipMemsetAsync(sums, 0, (size_t)NG * 64 * 4, stream);
    k_bin_hist<<<nbC, BS, 0, stream>>>(dst, hist, E, nbC);
    genscan1<<<gH, 512, 0, stream>>>(hist, bsums, nH);
    genscan2<<<1, 512, 0, stream>>>(bsums, gH);
    genscan3<<<gH, 512, 0, stream>>>(hist, bsums, nH);
    k_bin_scatter<<<nbC, BS, 0, stream>>>(src, dst, hist, ebuck, E, nbC);
    k_csrA<<<NBUK, BS, 0, stream>>>(ebuck, hist, row_ptr, dinv, N, nbC, NBUK, E);
    k_csrB<<<NBUK, BS, 0, stream>>>(ebuck, hist, row_ptr, dinv, csr, nbC);
    k_prepW<<<2, 512, 0, stream>>>(W2, W3, Wf2, Wf3);

    // ---- layer 1: fused pull + lin1 + relu -> h1 (h16) ----
    k_layer1<<<gN, BS, 0, stream>>>(row_ptr, csr, x, dinv, W1, b1, h16, N);

    // ---- layer 2: fused agg(h1) + lin2 + relu -> h2 (buf2) ----
    k_aggLin<1><<<gF, BS, 0, stream>>>(row_ptr, csr, h16, dinv, Wf2, b2, buf2, N);

    // ---- layer 3: fused agg(h2) + lin3 -> h3 (h16) ----
    k_aggLin<0><<<gF, BS, 0, stream>>>(row_ptr, csr, buf2, dinv, Wf3, b3, h16, N);

    // ---- pool + head ----
    k_pool_par<<<gP, BS, 0, stream>>>(h16, batch, sums, N);
    k_head<<<1, 128, 0, stream>>>(sums, batch, ge, Wl, bl, out, N, NG);
}

// Round 11
// 247.332 us; speedup vs baseline: 4.9042x; 1.0771x over previous
//
#include <hip/hip_runtime.h>
#include <hip/hip_bf16.h>
#include <math.h>

#define NG 128
#define CHUNKB 4096
#define NBIN 512     // dst buckets of 256 nodes; >= ceil(N/256)

typedef __attribute__((ext_vector_type(8))) short short8;
typedef __attribute__((ext_vector_type(4))) float float4v;

static __device__ __forceinline__ float bf2f(__hip_bfloat16 v) { return __bfloat162float(v); }

// ---------- per-chunk bucket histogram (LDS only, no global atomics) ----------
__global__ void k_bin_hist(const int* __restrict__ dst, int* __restrict__ hist,
                           int e, int nb) {
    __shared__ int h[NBIN];
    for (int i = threadIdx.x; i < NBIN; i += 256) h[i] = 0;
    __syncthreads();
    int base = blockIdx.x * CHUNKB;
    int lim = e - base; if (lim > CHUNKB) lim = CHUNKB;
    for (int k = threadIdx.x; k < lim; k += 256)
        atomicAdd(&h[dst[base + k] >> 8], 1);
    __syncthreads();
    for (int b = threadIdx.x; b < NBIN; b += 256) hist[b * nb + blockIdx.x] = h[b];
}

// ---------- generic exclusive scan (512-thread blocks) ----------
__global__ void __launch_bounds__(512) genscan1(int* __restrict__ a, int* __restrict__ bsums, int n) {
    __shared__ int s[512];
    int tid = threadIdx.x;
    int i = blockIdx.x * 512 + tid;
    int v = (i < n) ? a[i] : 0;
    s[tid] = v;
    __syncthreads();
    for (int d = 1; d < 512; d <<= 1) {
        int t = (tid >= d) ? s[tid - d] : 0;
        __syncthreads();
        s[tid] += t;
        __syncthreads();
    }
    if (i < n) a[i] = s[tid] - v;   // exclusive, in place
    if (tid == 511) bsums[blockIdx.x] = s[511];
}

__global__ void __launch_bounds__(512) genscan2(int* __restrict__ bsums, int nb) {
    __shared__ int s[512];
    int tid = threadIdx.x;
    int v = (tid < nb) ? bsums[tid] : 0;
    s[tid] = v;
    __syncthreads();
    for (int d = 1; d < 512; d <<= 1) {
        int t = (tid >= d) ? s[tid - d] : 0;
        __syncthreads();
        s[tid] += t;
        __syncthreads();
    }
    if (tid < nb) bsums[tid] = s[tid] - v;
}

__global__ void __launch_bounds__(512) genscan3(int* __restrict__ a, const int* __restrict__ bsums, int n) {
    int i = blockIdx.x * 512 + threadIdx.x;
    if (i < n) a[i] += bsums[blockIdx.x];
}

// ---------- LDS-staged bucket scatter (exact offsets, clustered writes) ----------
__global__ void k_bin_scatter(const int* __restrict__ srcs, const int* __restrict__ dsts,
                              const int* __restrict__ offsets, int2* __restrict__ outbuf,
                              int e, int nb) {
    __shared__ int hcnt[NBIN];     // counts -> cursor
    __shared__ int lstart[NBIN];   // local start -> delta
    __shared__ int ss[256];
    __shared__ int2 stage[CHUNKB];
    int tid = threadIdx.x, blk = blockIdx.x, base = blk * CHUNKB;
    int lim = e - base; if (lim > CHUNKB) lim = CHUNKB;
    for (int i = tid; i < NBIN; i += 256) hcnt[i] = 0;
    __syncthreads();
    for (int k = tid; k < lim; k += 256)
        atomicAdd(&hcnt[dsts[base + k] >> 8], 1);
    __syncthreads();
    int c0 = hcnt[2 * tid], c1 = hcnt[2 * tid + 1];
    int sum = c0 + c1;
    ss[tid] = sum;
    __syncthreads();
    for (int d = 1; d < 256; d <<= 1) {
        int t = (tid >= d) ? ss[tid - d] : 0;
        __syncthreads();
        ss[tid] += t;
        __syncthreads();
    }
    int excl = ss[tid] - sum;
    lstart[2 * tid] = excl;
    lstart[2 * tid + 1] = excl + c0;
    __syncthreads();
    hcnt[2 * tid] = excl;          // cursors
    hcnt[2 * tid + 1] = excl + c0;
    __syncthreads();
    for (int k = tid; k < lim; k += 256) {
        int2 ed = make_int2(srcs[base + k], dsts[base + k]);
        int p = atomicAdd(&hcnt[ed.y >> 8], 1);
        stage[p] = ed;
    }
    __syncthreads();
    for (int i = tid; i < NBIN; i += 256) lstart[i] = offsets[i * nb + blk] - lstart[i];
    __syncthreads();
    for (int p = tid; p < lim; p += 256) {
        int2 ed = stage[p];
        outbuf[lstart[ed.y >> 8] + p] = ed;
    }
}

// ---------- block per bucket: per-node degree (LDS), row_ptr, dinv ----------
__global__ void k_csrA(const int2* __restrict__ ebuck, const int* __restrict__ offsets,
                       int* __restrict__ row_ptr, float* __restrict__ dinv,
                       int n, int nb, int nbuk, int e_total) {
    __shared__ int lcnt[256];
    __shared__ int ssc[256];
    int b = blockIdx.x, tid = threadIdx.x, n0 = b << 8;
    lcnt[tid] = 0;
    __syncthreads();
    int e0 = offsets[b * nb];
    int e1 = offsets[(b + 1) * nb];
    for (int i = e0 + tid; i < e1; i += 256)
        atomicAdd(&lcnt[ebuck[i].y - n0], 1);
    __syncthreads();
    int v = lcnt[tid];
    ssc[tid] = v;
    __syncthreads();
    for (int d = 1; d < 256; d <<= 1) {
        int t = (tid >= d) ? ssc[tid - d] : 0;
        __syncthreads();
        ssc[tid] += t;
        __syncthreads();
    }
    int node = n0 + tid;
    if (node < n) {
        row_ptr[node] = e0 + ssc[tid] - v;   // exclusive
        dinv[node] = rsqrtf((float)v + 1.0f);
        if (node == n - 1) row_ptr[n] = e_total;
    }
}

// ---------- block per bucket: place edges at exact CSR pos, precompute w ----------
__global__ void k_csrB(const int2* __restrict__ ebuck, const int* __restrict__ offsets,
                       const int* __restrict__ row_ptr, const float* __restrict__ dinv,
                       int2* __restrict__ csr, int nb) {
    __shared__ int lcur[256];
    int b = blockIdx.x, tid = threadIdx.x, n0 = b << 8;
    lcur[tid] = 0;
    __syncthreads();
    int e0 = offsets[b * nb];
    int e1 = offsets[(b + 1) * nb];
    for (int i = e0 + tid; i < e1; i += 256) {
        int2 ed = ebuck[i];
        int r = atomicAdd(&lcur[ed.y - n0], 1);
        int pos = row_ptr[ed.y] + r;
        float w = dinv[ed.x] * dinv[ed.y];
        csr[pos] = make_int2(ed.x, __float_as_int(w));
    }
}

// ---------- layer 1 fused: pull on x (2 feats) + lin1 + relu -> h1 bf16 ----------
__global__ void k_layer1(const int* __restrict__ row_ptr, const int2* __restrict__ edges,
                         const float* __restrict__ x, const float* __restrict__ dinv,
                         const float* __restrict__ W1, const float* __restrict__ b1,
                         __hip_bfloat16* __restrict__ h, int n) {
    __shared__ float w1s[128];
    __shared__ float b1s[64];
    if (threadIdx.x < 128) w1s[threadIdx.x] = W1[threadIdx.x];
    if (threadIdx.x < 64) b1s[threadIdx.x] = b1[threadIdx.x];
    __syncthreads();
    int i = blockIdx.x * blockDim.x + threadIdx.x;
    if (i >= n) return;
    const float2* x2 = (const float2*)x;
    float dd = dinv[i], d2 = dd * dd;
    float2 xi = x2[i];
    float a0 = d2 * xi.x, a1 = d2 * xi.y;
    int lo = row_ptr[i], hi = row_ptr[i + 1];
    int k = lo;
    for (; k + 4 <= hi; k += 4) {
        int2 e0 = edges[k], e1 = edges[k + 1], e2 = edges[k + 2], e3 = edges[k + 3];
        float2 v0 = x2[e0.x], v1 = x2[e1.x], v2 = x2[e2.x], v3 = x2[e3.x];
        a0 += __int_as_float(e0.y) * v0.x; a1 += __int_as_float(e0.y) * v0.y;
        a0 += __int_as_float(e1.y) * v1.x; a1 += __int_as_float(e1.y) * v1.y;
        a0 += __int_as_float(e2.y) * v2.x; a1 += __int_as_float(e2.y) * v2.y;
        a0 += __int_as_float(e3.y) * v3.x; a1 += __int_as_float(e3.y) * v3.y;
    }
    for (; k < hi; k++) {
        int2 e = edges[k];
        float2 v = x2[e.x];
        a0 += __int_as_float(e.y) * v.x;
        a1 += __int_as_float(e.y) * v.y;
    }
    short8* hv = reinterpret_cast<short8*>(h + (size_t)i * 64);
    #pragma unroll
    for (int g = 0; g < 8; g++) {
        short8 pack;
        #pragma unroll
        for (int j = 0; j < 8; j++) {
            int col = g * 8 + j;
            float v = fmaxf(a0 * w1s[col] + a1 * w1s[64 + col] + b1s[col], 0.0f);
            __hip_bfloat16 bv = __float2bfloat16(v);
            pack[j] = *reinterpret_cast<short*>(&bv);
        }
        hv[g] = pack;
    }
}

// ---------- fused agg + MFMA linear: wave = 16 nodes ----------
// Gather phase uses paired-feature lanes: lane = (half, col); col in [0,32)
// owns packed features (2col, 2col+1) as one uint; half selects which edge of
// a pair the lane serves. Per 8 ILP slots, 16 edges are gathered.
template <int RELU>
__global__ void __launch_bounds__(256) k_aggLin(const int* __restrict__ row_ptr,
                                                const int2* __restrict__ edges,
                                                const __hip_bfloat16* __restrict__ hin,
                                                const float* __restrict__ dinv,
                                                const __hip_bfloat16* __restrict__ Wf,
                                                const float* __restrict__ b,
                                                __hip_bfloat16* __restrict__ hout, int n) {
    __shared__ __attribute__((aligned(16))) __hip_bfloat16 tile[4][16 * 72]; // stride 72: 16B-aligned rows
    int wave = threadIdx.x >> 6, lane = threadIdx.x & 63;
    int nb0 = (blockIdx.x * 4 + wave) * 16;
    if (nb0 >= n) return;
    __hip_bfloat16* T = &tile[wave][0];
    int half = lane >> 5;      // which edge of each pair
    int col  = lane & 31;      // feature pair index
    const uint* hinu = reinterpret_cast<const uint*>(hin);

    for (int nn = 0; nn < 16; nn++) {
        int node = nb0 + nn;
        float ax = 0.0f, ay = 0.0f;
        if (node < n) {
            if (half == 0) {               // self term counted once
                float dn = dinv[node];
                uint hv = hinu[(size_t)node * 32 + col];
                float dn2 = dn * dn;
                ax = dn2 * __int_as_float(hv << 16);
                ay = dn2 * __int_as_float(hv & 0xffff0000u);
            }
            int lo = row_ptr[node], hi = row_ptr[node + 1];
            for (int base = lo; base < hi; base += 64) {
                int take = hi - base; if (take > 64) take = 64;
                int take16 = (take + 15) & ~15;    // 8 slots x 2 edges per round
                int sl = 0; float wl = 0.0f;
                if (base + lane < hi) {
                    int2 e = edges[base + lane];   // coalesced
                    sl = e.x; wl = __int_as_float(e.y);
                }
                for (int k = 0; k < take16; k += 16) {
                    int kb = k + half;
                    int   s0 = __shfl(sl, kb),      s1 = __shfl(sl, kb + 2);
                    int   s2 = __shfl(sl, kb + 4),  s3 = __shfl(sl, kb + 6);
                    int   s4 = __shfl(sl, kb + 8),  s5 = __shfl(sl, kb + 10);
                    int   s6 = __shfl(sl, kb + 12), s7 = __shfl(sl, kb + 14);
                    float w0 = __shfl(wl, kb),      w1 = __shfl(wl, kb + 2);
                    float w2 = __shfl(wl, kb + 4),  w3 = __shfl(wl, kb + 6);
                    float w4 = __shfl(wl, kb + 8),  w5 = __shfl(wl, kb + 10);
                    float w6 = __shfl(wl, kb + 12), w7 = __shfl(wl, kb + 14);
                    uint v0 = hinu[(size_t)s0 * 32 + col];
                    uint v1 = hinu[(size_t)s1 * 32 + col];
                    uint v2 = hinu[(size_t)s2 * 32 + col];
                    uint v3 = hinu[(size_t)s3 * 32 + col];
                    uint v4 = hinu[(size_t)s4 * 32 + col];
                    uint v5 = hinu[(size_t)s5 * 32 + col];
                    uint v6 = hinu[(size_t)s6 * 32 + col];
                    uint v7 = hinu[(size_t)s7 * 32 + col];
                    ax += w0 * __int_as_float(v0 << 16); ay += w0 * __int_as_float(v0 & 0xffff0000u);
                    ax += w1 * __int_as_float(v1 << 16); ay += w1 * __int_as_float(v1 & 0xffff0000u);
                    ax += w2 * __int_as_float(v2 << 16); ay += w2 * __int_as_float(v2 & 0xffff0000u);
                    ax += w3 * __int_as_float(v3 << 16); ay += w3 * __int_as_float(v3 & 0xffff0000u);
                    ax += w4 * __int_as_float(v4 << 16); ay += w4 * __int_as_float(v4 & 0xffff0000u);
                    ax += w5 * __int_as_float(v5 << 16); ay += w5 * __int_as_float(v5 & 0xffff0000u);
                    ax += w6 * __int_as_float(v6 << 16); ay += w6 * __int_as_float(v6 & 0xffff0000u);
                    ax += w7 * __int_as_float(v7 << 16); ay += w7 * __int_as_float(v7 & 0xffff0000u);
                }
            }
        }
        // cross-half reduce: both halves end with the full sum
        ax += __shfl_xor(ax, 32);
        ay += __shfl_xor(ay, 32);
        if (half == 0) {
            __hip_bfloat16 bx = __float2bfloat16(ax);
            __hip_bfloat16 by = __float2bfloat16(ay);
            uint pack = (uint)(*reinterpret_cast<unsigned short*>(&bx)) |
                        ((uint)(*reinterpret_cast<unsigned short*>(&by)) << 16);
            *reinterpret_cast<uint*>(&T[nn * 72 + 2 * col]) = pack;
        }
    }

    // MFMA phase on the wave's 16x64 tile
    int m = lane & 15, q = lane >> 4;
    short8 a0 = *reinterpret_cast<const short8*>(&T[m * 72 + q * 8]);
    short8 a1 = *reinterpret_cast<const short8*>(&T[m * 72 + 32 + q * 8]);
    #pragma unroll
    for (int jt = 0; jt < 4; jt++) {
        short8 bf0 = *reinterpret_cast<const short8*>(Wf + ((size_t)(jt * 2 + 0) * 64 + lane) * 8);
        short8 bf1 = *reinterpret_cast<const short8*>(Wf + ((size_t)(jt * 2 + 1) * 64 + lane) * 8);
        float4v d = {0.0f, 0.0f, 0.0f, 0.0f};
        d = __builtin_amdgcn_mfma_f32_16x16x32_bf16(a0, bf0, d, 0, 0, 0);
        d = __builtin_amdgcn_mfma_f32_16x16x32_bf16(a1, bf1, d, 0, 0, 0);
        float bias = b[jt * 16 + m];           // C/D col = lane&15
        #pragma unroll
        for (int r = 0; r < 4; r++) {
            int row = q * 4 + r;               // C/D row = quad*4 + reg
            int node = nb0 + row;
            if (node < n) {
                float v = d[r] + bias;
                if (RELU) v = fmaxf(v, 0.0f);
                hout[(size_t)node * 64 + jt * 16 + m] = __float2bfloat16(v);
            }
        }
    }
}

// ---------- pack W (64x64 fp32) into MFMA B-fragment order, bf16 ----------
__global__ void k_prepW(const float* __restrict__ W2, const float* __restrict__ W3,
                        __hip_bfloat16* __restrict__ Wf2, __hip_bfloat16* __restrict__ Wf3) {
    const float* W = blockIdx.x ? W3 : W2;
    __hip_bfloat16* Wf = blockIdx.x ? Wf3 : Wf2;
    int t = threadIdx.x;           // 0..511
    int c = t >> 6, l = t & 63;
    int jt = c >> 1, half = c & 1, nn = l & 15, q = l >> 4;
    #pragma unroll
    for (int j = 0; j < 8; j++) {
        int k = half * 32 + q * 8 + j;
        Wf[t * 8 + j] = __float2bfloat16(W[k * 64 + jt * 16 + nn]);
    }
}

// ---------- node-parallel pool ----------
__global__ void k_pool_par(const __hip_bfloat16* __restrict__ h,
                           const int* __restrict__ batch,
                           float* __restrict__ sums, int n) {
    int base = blockIdx.x * 128;
    int lim = base + 128; if (lim > n) lim = n;
    int j = threadIdx.x & 63, r = threadIdx.x >> 6;
    float acc = 0.0f; int gcur = -1;
    for (int i = base + r; i < lim; i += 4) {
        int g = batch[i];
        if (g != gcur) {
            if (gcur >= 0) atomicAdd(&sums[gcur * 64 + j], acc);
            acc = 0.0f; gcur = g;
        }
        acc += bf2f(h[(size_t)i * 64 + j]);
    }
    if (gcur >= 0) atomicAdd(&sums[gcur * 64 + j], acc);
}

// ---------- head ----------
__device__ inline int lower_bound_i(const int* __restrict__ a, int n, int key) {
    int lo = 0, hi = n;
    while (lo < hi) {
        int mid = (lo + hi) >> 1;
        if (a[mid] < key) lo = mid + 1; else hi = mid;
    }
    return lo;
}

__global__ void k_head(const float* __restrict__ sums, const int* __restrict__ batch,
                       const float* __restrict__ ge, const float* __restrict__ Wl,
                       const float* __restrict__ bl, float* __restrict__ out,
                       int n, int ng) {
    int g = blockIdx.x * blockDim.x + threadIdx.x;
    if (g < ng) {
        int lo = lower_bound_i(batch, n, g);
        int hi = lower_bound_i(batch, n, g + 1);
        float c = fmaxf((float)(hi - lo), 1.0f);
        float z[5];
        for (int cl = 0; cl < 5; cl++) z[cl] = bl[cl];
        for (int k = 0; k < 64; k++) {
            float p = sums[g * 64 + k] / c;
            for (int cl = 0; cl < 5; cl++) z[cl] += p * Wl[k * 5 + cl];
        }
        for (int k = 0; k < 64; k++) {
            float p = ge[g * 64 + k];
            for (int cl = 0; cl < 5; cl++) z[cl] += p * Wl[(64 + k) * 5 + cl];
        }
        float m = z[0];
        for (int cl = 1; cl < 5; cl++) m = fmaxf(m, z[cl]);
        float s = 0.0f;
        for (int cl = 0; cl < 5; cl++) s += expf(z[cl] - m);
        float lse = m + logf(s);
        for (int cl = 0; cl < 5; cl++) out[g * 5 + cl] = z[cl] - lse;
    }
}

#define ALIGN16(x) (((x) + 15) & ~(size_t)15)

extern "C" void kernel_launch(void* const* d_in, const int* in_sizes, int n_in,
                              void* d_out, int out_size, void* d_ws, size_t ws_size,
                              hipStream_t stream) {
    const float* x    = (const float*)d_in[0];
    const int*   ei   = (const int*)d_in[1];
    const int*   batch= (const int*)d_in[2];
    const float* ge   = (const float*)d_in[3];
    const float* W1   = (const float*)d_in[4];
    const float* b1   = (const float*)d_in[5];
    const float* W2   = (const float*)d_in[6];
    const float* b2   = (const float*)d_in[7];
    const float* W3   = (const float*)d_in[8];
    const float* b3   = (const float*)d_in[9];
    const float* Wl   = (const float*)d_in[10];
    const float* bl   = (const float*)d_in[11];
    float* out = (float*)d_out;

    const int N = in_sizes[0] / 2;   // x is [N,2]
    const int E = in_sizes[1] / 2;   // edge_index is [2,E]
    const int* src = ei;
    const int* dst = ei + E;
    const int NBUK = (N + 255) >> 8;             // actual dst buckets (<= NBIN)
    const int nbC  = (E + CHUNKB - 1) / CHUNKB;  // sort chunks

    // ---- workspace layout (segments 16B-aligned) ----
    char* wsb = (char*)d_ws;
    float* dinv   = (float*)wsb;                wsb += ALIGN16((size_t)N * 4);
    __hip_bfloat16* h16 = (__hip_bfloat16*)wsb;  wsb += ALIGN16((size_t)64 * N * 2);  // h1 / h3
    __hip_bfloat16* buf2= (__hip_bfloat16*)wsb;  wsb += ALIGN16((size_t)64 * N * 2);  // h2
    float* sums   = (float*)wsb;                wsb += ALIGN16((size_t)NG * 64 * 4);
    __hip_bfloat16* Wf2 = (__hip_bfloat16*)wsb; wsb += ALIGN16((size_t)4096 * 2);
    __hip_bfloat16* Wf3 = (__hip_bfloat16*)wsb; wsb += ALIGN16((size_t)4096 * 2);
    int2*  ebuck  = (int2*)wsb;                 wsb += ALIGN16((size_t)E * 8);
    int2*  csr    = (int2*)wsb;                 wsb += ALIGN16((size_t)E * 8);
    int*   row_ptr= (int*)wsb;                  wsb += ALIGN16((size_t)(N + 1) * 4);
    int*   hist   = (int*)wsb;                  wsb += ALIGN16((size_t)NBIN * nbC * 4);
    int*   bsums  = (int*)wsb;                  wsb += 512 * 4;

    const int BS = 256;
    int gN   = (N + BS - 1) / BS;
    int gF   = ((N + 15) / 16 + 3) / 4;          // k_aggLin: 4 waves * 16 nodes
    int gP   = (N + 127) / 128;                  // pool chunks
    int nH   = NBIN * nbC;
    int gH   = (nH + 511) / 512;                 // <= 512 for genscan2

    // ---- CSR build: single-pass bucket sort, all histograms in LDS ----
    hipMemsetAsync(sums, 0, (size_t)NG * 64 * 4, stream);
    k_bin_hist<<<nbC, BS, 0, stream>>>(dst, hist, E, nbC);
    genscan1<<<gH, 512, 0, stream>>>(hist, bsums, nH);
    genscan2<<<1, 512, 0, stream>>>(bsums, gH);
    genscan3<<<gH, 512, 0, stream>>>(hist, bsums, nH);
    k_bin_scatter<<<nbC, BS, 0, stream>>>(src, dst, hist, ebuck, E, nbC);
    k_csrA<<<NBUK, BS, 0, stream>>>(ebuck, hist, row_ptr, dinv, N, nbC, NBUK, E);
    k_csrB<<<NBUK, BS, 0, stream>>>(ebuck, hist, row_ptr, dinv, csr, nbC);
    k_prepW<<<2, 512, 0, stream>>>(W2, W3, Wf2, Wf3);

    // ---- layer 1: fused pull + lin1 + relu -> h1 (h16) ----
    k_layer1<<<gN, BS, 0, stream>>>(row_ptr, csr, x, dinv, W1, b1, h16, N);

    // ---- layer 2: fused agg(h1) + lin2 + relu -> h2 (buf2) ----
    k_aggLin<1><<<gF, BS, 0, stream>>>(row_ptr, csr, h16, dinv, Wf2, b2, buf2, N);

    // ---- layer 3: fused agg(h2) + lin3 -> h3 (h16) ----
    k_aggLin<0><<<gF, BS, 0, stream>>>(row_ptr, csr, buf2, dinv, Wf3, b3, h16, N);

    // ---- pool + head ----
    k_pool_par<<<gP, BS, 0, stream>>>(h16, batch, sums, N);
    k_head<<<1, 128, 0, stream>>>(sums, batch, ge, Wl, bl, out, N, NG);
}

// Round 12
// 245.669 us; speedup vs baseline: 4.9374x; 1.0068x over previous
//
#include <hip/hip_runtime.h>
#include <hip/hip_bf16.h>
#include <math.h>

#define NG 128
#define CHUNKB 4096
#define NBIN 512     // dst buckets of 256 nodes; >= ceil(N/256)
#define EWIN 320     // per-wave LDS edge window (16 nodes, avg deg 10 -> ~160)

typedef __attribute__((ext_vector_type(8))) short short8;
typedef __attribute__((ext_vector_type(4))) float float4v;

static __device__ __forceinline__ float bf2f(__hip_bfloat16 v) { return __bfloat162float(v); }

// ---------- per-chunk bucket histogram (LDS only, no global atomics) ----------
__global__ void k_bin_hist(const int* __restrict__ dst, int* __restrict__ hist,
                           int e, int nb) {
    __shared__ int h[NBIN];
    for (int i = threadIdx.x; i < NBIN; i += 256) h[i] = 0;
    __syncthreads();
    int base = blockIdx.x * CHUNKB;
    int lim = e - base; if (lim > CHUNKB) lim = CHUNKB;
    for (int k = threadIdx.x; k < lim; k += 256)
        atomicAdd(&h[dst[base + k] >> 8], 1);
    __syncthreads();
    for (int b = threadIdx.x; b < NBIN; b += 256) hist[b * nb + blockIdx.x] = h[b];
}

// ---------- generic exclusive scan (512-thread blocks) ----------
__global__ void __launch_bounds__(512) genscan1(int* __restrict__ a, int* __restrict__ bsums, int n) {
    __shared__ int s[512];
    int tid = threadIdx.x;
    int i = blockIdx.x * 512 + tid;
    int v = (i < n) ? a[i] : 0;
    s[tid] = v;
    __syncthreads();
    for (int d = 1; d < 512; d <<= 1) {
        int t = (tid >= d) ? s[tid - d] : 0;
        __syncthreads();
        s[tid] += t;
        __syncthreads();
    }
    if (i < n) a[i] = s[tid] - v;   // exclusive, in place
    if (tid == 511) bsums[blockIdx.x] = s[511];
}

__global__ void __launch_bounds__(512) genscan2(int* __restrict__ bsums, int nb) {
    __shared__ int s[512];
    int tid = threadIdx.x;
    int v = (tid < nb) ? bsums[tid] : 0;
    s[tid] = v;
    __syncthreads();
    for (int d = 1; d < 512; d <<= 1) {
        int t = (tid >= d) ? s[tid - d] : 0;
        __syncthreads();
        s[tid] += t;
        __syncthreads();
    }
    if (tid < nb) bsums[tid] = s[tid] - v;
}
// genscan3 is fused into consumers: offset(i) = hist[i] + bsums[i >> 9]

// ---------- LDS-staged bucket scatter (exact offsets, clustered writes) ----------
__global__ void k_bin_scatter(const int* __restrict__ srcs, const int* __restrict__ dsts,
                              const int* __restrict__ offsets, const int* __restrict__ bsums,
                              int2* __restrict__ outbuf, int e, int nb) {
    __shared__ int hcnt[NBIN];     // counts -> cursor
    __shared__ int lstart[NBIN];   // local start -> delta
    __shared__ int ss[256];
    __shared__ int2 stage[CHUNKB];
    int tid = threadIdx.x, blk = blockIdx.x, base = blk * CHUNKB;
    int lim = e - base; if (lim > CHUNKB) lim = CHUNKB;
    for (int i = tid; i < NBIN; i += 256) hcnt[i] = 0;
    __syncthreads();
    for (int k = tid; k < lim; k += 256)
        atomicAdd(&hcnt[dsts[base + k] >> 8], 1);
    __syncthreads();
    int c0 = hcnt[2 * tid], c1 = hcnt[2 * tid + 1];
    int sum = c0 + c1;
    ss[tid] = sum;
    __syncthreads();
    for (int d = 1; d < 256; d <<= 1) {
        int t = (tid >= d) ? ss[tid - d] : 0;
        __syncthreads();
        ss[tid] += t;
        __syncthreads();
    }
    int excl = ss[tid] - sum;
    lstart[2 * tid] = excl;
    lstart[2 * tid + 1] = excl + c0;
    __syncthreads();
    hcnt[2 * tid] = excl;          // cursors
    hcnt[2 * tid + 1] = excl + c0;
    __syncthreads();
    for (int k = tid; k < lim; k += 256) {
        int2 ed = make_int2(srcs[base + k], dsts[base + k]);
        int p = atomicAdd(&hcnt[ed.y >> 8], 1);
        stage[p] = ed;
    }
    __syncthreads();
    for (int i = tid; i < NBIN; i += 256) {
        int gi = i * nb + blk;
        lstart[i] = offsets[gi] + bsums[gi >> 9] - lstart[i];
    }
    __syncthreads();
    for (int p = tid; p < lim; p += 256) {
        int2 ed = stage[p];
        outbuf[lstart[ed.y >> 8] + p] = ed;
    }
}

// ---------- block per bucket: per-node degree (LDS), row_ptr, dinv ----------
__global__ void k_csrA(const int2* __restrict__ ebuck, const int* __restrict__ offsets,
                       const int* __restrict__ bsums, int* __restrict__ row_ptr,
                       float* __restrict__ dinv, int n, int nb, int nbuk, int e_total) {
    __shared__ int lcnt[256];
    __shared__ int ssc[256];
    int b = blockIdx.x, tid = threadIdx.x, n0 = b << 8;
    lcnt[tid] = 0;
    __syncthreads();
    int i0 = b * nb, i1 = (b + 1) * nb;
    int e0 = offsets[i0] + bsums[i0 >> 9];
    int e1 = offsets[i1] + bsums[i1 >> 9];
    for (int i = e0 + tid; i < e1; i += 256)
        atomicAdd(&lcnt[ebuck[i].y - n0], 1);
    __syncthreads();
    int v = lcnt[tid];
    ssc[tid] = v;
    __syncthreads();
    for (int d = 1; d < 256; d <<= 1) {
        int t = (tid >= d) ? ssc[tid - d] : 0;
        __syncthreads();
        ssc[tid] += t;
        __syncthreads();
    }
    int node = n0 + tid;
    if (node < n) {
        row_ptr[node] = e0 + ssc[tid] - v;   // exclusive
        dinv[node] = rsqrtf((float)v + 1.0f);
        if (node == n - 1) row_ptr[n] = e_total;
    }
}

// ---------- block per bucket: place edges at exact CSR pos, precompute w ----------
__global__ void k_csrB(const int2* __restrict__ ebuck, const int* __restrict__ offsets,
                       const int* __restrict__ bsums, const int* __restrict__ row_ptr,
                       const float* __restrict__ dinv, int2* __restrict__ csr, int nb) {
    __shared__ int lcur[256];
    int b = blockIdx.x, tid = threadIdx.x, n0 = b << 8;
    lcur[tid] = 0;
    __syncthreads();
    int i0 = b * nb, i1 = (b + 1) * nb;
    int e0 = offsets[i0] + bsums[i0 >> 9];
    int e1 = offsets[i1] + bsums[i1 >> 9];
    for (int i = e0 + tid; i < e1; i += 256) {
        int2 ed = ebuck[i];
        int r = atomicAdd(&lcur[ed.y - n0], 1);
        int pos = row_ptr[ed.y] + r;
        float w = dinv[ed.x] * dinv[ed.y];
        csr[pos] = make_int2(ed.x, __float_as_int(w));
    }
}

// ---------- layer 1 fused: pull on x (2 feats) + lin1 + relu -> h1 bf16 ----------
__global__ void k_layer1(const int* __restrict__ row_ptr, const int2* __restrict__ edges,
                         const float* __restrict__ x, const float* __restrict__ dinv,
                         const float* __restrict__ W1, const float* __restrict__ b1,
                         __hip_bfloat16* __restrict__ h, int n) {
    __shared__ float w1s[128];
    __shared__ float b1s[64];
    if (threadIdx.x < 128) w1s[threadIdx.x] = W1[threadIdx.x];
    if (threadIdx.x < 64) b1s[threadIdx.x] = b1[threadIdx.x];
    __syncthreads();
    int i = blockIdx.x * blockDim.x + threadIdx.x;
    if (i >= n) return;
    const float2* x2 = (const float2*)x;
    float dd = dinv[i], d2 = dd * dd;
    float2 xi = x2[i];
    float a0 = d2 * xi.x, a1 = d2 * xi.y;
    int lo = row_ptr[i], hi = row_ptr[i + 1];
    int k = lo;
    for (; k + 4 <= hi; k += 4) {
        int2 e0 = edges[k], e1 = edges[k + 1], e2 = edges[k + 2], e3 = edges[k + 3];
        float2 v0 = x2[e0.x], v1 = x2[e1.x], v2 = x2[e2.x], v3 = x2[e3.x];
        a0 += __int_as_float(e0.y) * v0.x; a1 += __int_as_float(e0.y) * v0.y;
        a0 += __int_as_float(e1.y) * v1.x; a1 += __int_as_float(e1.y) * v1.y;
        a0 += __int_as_float(e2.y) * v2.x; a1 += __int_as_float(e2.y) * v2.y;
        a0 += __int_as_float(e3.y) * v3.x; a1 += __int_as_float(e3.y) * v3.y;
    }
    for (; k < hi; k++) {
        int2 e = edges[k];
        float2 v = x2[e.x];
        a0 += __int_as_float(e.y) * v.x;
        a1 += __int_as_float(e.y) * v.y;
    }
    short8* hv = reinterpret_cast<short8*>(h + (size_t)i * 64);
    #pragma unroll
    for (int g = 0; g < 8; g++) {
        short8 pack;
        #pragma unroll
        for (int j = 0; j < 8; j++) {
            int col = g * 8 + j;
            float v = fmaxf(a0 * w1s[col] + a1 * w1s[64 + col] + b1s[col], 0.0f);
            __hip_bfloat16 bv = __float2bfloat16(v);
            pack[j] = *reinterpret_cast<short*>(&bv);
        }
        hv[g] = pack;
    }
}

// ---------- per-node gather core (edges from LDS window or global) ----------
template <bool FAST>
static __device__ __forceinline__ void agg_node(int lo, int hi, int half, int col,
        const int2* __restrict__ gE, const int2* EW, int wave_lo,
        const uint* __restrict__ hinu, float& ax, float& ay) {
    for (int k = lo; k < hi; k += 16) {
        int ss[8]; float ww[8];
        #pragma unroll
        for (int j = 0; j < 8; j++) {
            int idx = k + 2 * j + half;
            int cidx = idx < hi ? idx : lo;      // clamped, always valid
            int2 ee = FAST ? EW[cidx - wave_lo] : gE[cidx];
            ss[j] = ee.x;
            ww[j] = idx < hi ? __int_as_float(ee.y) : 0.0f;
        }
        uint vv[8];
        #pragma unroll
        for (int j = 0; j < 8; j++) vv[j] = hinu[(size_t)ss[j] * 32 + col];
        #pragma unroll
        for (int j = 0; j < 8; j++) {
            ax += ww[j] * __int_as_float(vv[j] << 16);
            ay += ww[j] * __int_as_float(vv[j] & 0xffff0000u);
        }
    }
}

// ---------- fused agg + MFMA linear: wave = 16 nodes ----------
// The wave's 16 consecutive nodes own a contiguous CSR range; stage it ONCE
// into a wave-private LDS window (kills the 6.4x per-node edge re-load waste),
// then gather with paired-feature lanes: lane = (half, col).
template <int RELU>
__global__ void __launch_bounds__(256) k_aggLin(const int* __restrict__ row_ptr,
                                                const int2* __restrict__ edges,
                                                const __hip_bfloat16* __restrict__ hin,
                                                const float* __restrict__ dinv,
                                                const __hip_bfloat16* __restrict__ Wf,
                                                const float* __restrict__ b,
                                                __hip_bfloat16* __restrict__ hout, int n) {
    __shared__ __attribute__((aligned(16))) __hip_bfloat16 tile[4][16 * 72];
    __shared__ int2 ewin[4][EWIN];
    int wave = threadIdx.x >> 6, lane = threadIdx.x & 63;
    int nb0 = (blockIdx.x * 4 + wave) * 16;
    if (nb0 >= n) return;
    __hip_bfloat16* T = &tile[wave][0];
    int2* EW = &ewin[wave][0];
    int half = lane >> 5, col = lane & 31;
    const uint* hinu = reinterpret_cast<const uint*>(hin);

    // lanes 0..16 hold the 17 row_ptr boundaries for this wave's nodes
    int bidx = nb0 + (lane < 16 ? lane : 16);
    if (bidx > n) bidx = n;
    int rp = row_ptr[bidx];
    int wave_lo = __shfl(rp, 0);
    int wave_hi = __shfl(rp, 16);
    int cnt = wave_hi - wave_lo;
    bool fast = (cnt <= EWIN);
    if (fast)
        for (int i = lane; i < cnt; i += 64) EW[i] = edges[wave_lo + i];
    // same-wave LDS write->read ordering (in-order LDS pipe; R10/R11 precedent)

    for (int nn = 0; nn < 16; nn++) {
        int node = nb0 + nn;
        float ax = 0.0f, ay = 0.0f;
        if (node < n) {
            if (half == 0) {               // self term counted once
                float dn = dinv[node];
                uint hv = hinu[(size_t)node * 32 + col];
                float dn2 = dn * dn;
                ax = dn2 * __int_as_float(hv << 16);
                ay = dn2 * __int_as_float(hv & 0xffff0000u);
            }
            int lo = __shfl(rp, nn), hi = __shfl(rp, nn + 1);
            if (fast) agg_node<true >(lo, hi, half, col, edges, EW, wave_lo, hinu, ax, ay);
            else      agg_node<false>(lo, hi, half, col, edges, EW, wave_lo, hinu, ax, ay);
        }
        // cross-half reduce
        ax += __shfl_xor(ax, 32);
        ay += __shfl_xor(ay, 32);
        if (half == 0) {
            __hip_bfloat16 bx = __float2bfloat16(ax);
            __hip_bfloat16 by = __float2bfloat16(ay);
            uint pack = (uint)(*reinterpret_cast<unsigned short*>(&bx)) |
                        ((uint)(*reinterpret_cast<unsigned short*>(&by)) << 16);
            *reinterpret_cast<uint*>(&T[nn * 72 + 2 * col]) = pack;
        }
    }

    // MFMA phase on the wave's 16x64 tile
    int m = lane & 15, q = lane >> 4;
    short8 a0 = *reinterpret_cast<const short8*>(&T[m * 72 + q * 8]);
    short8 a1 = *reinterpret_cast<const short8*>(&T[m * 72 + 32 + q * 8]);
    #pragma unroll
    for (int jt = 0; jt < 4; jt++) {
        short8 bf0 = *reinterpret_cast<const short8*>(Wf + ((size_t)(jt * 2 + 0) * 64 + lane) * 8);
        short8 bf1 = *reinterpret_cast<const short8*>(Wf + ((size_t)(jt * 2 + 1) * 64 + lane) * 8);
        float4v d = {0.0f, 0.0f, 0.0f, 0.0f};
        d = __builtin_amdgcn_mfma_f32_16x16x32_bf16(a0, bf0, d, 0, 0, 0);
        d = __builtin_amdgcn_mfma_f32_16x16x32_bf16(a1, bf1, d, 0, 0, 0);
        float bias = b[jt * 16 + m];           // C/D col = lane&15
        #pragma unroll
        for (int r = 0; r < 4; r++) {
            int row = q * 4 + r;               // C/D row = quad*4 + reg
            int node = nb0 + row;
            if (node < n) {
                float v = d[r] + bias;
                if (RELU) v = fmaxf(v, 0.0f);
                hout[(size_t)node * 64 + jt * 16 + m] = __float2bfloat16(v);
            }
        }
    }
}

// ---------- pack W (64x64 fp32) into MFMA B-fragment order, bf16 ----------
__global__ void k_prepW(const float* __restrict__ W2, const float* __restrict__ W3,
                        __hip_bfloat16* __restrict__ Wf2, __hip_bfloat16* __restrict__ Wf3) {
    const float* W = blockIdx.x ? W3 : W2;
    __hip_bfloat16* Wf = blockIdx.x ? Wf3 : Wf2;
    int t = threadIdx.x;           // 0..511
    int c = t >> 6, l = t & 63;
    int jt = c >> 1, half = c & 1, nn = l & 15, q = l >> 4;
    #pragma unroll
    for (int j = 0; j < 8; j++) {
        int k = half * 32 + q * 8 + j;
        Wf[t * 8 + j] = __float2bfloat16(W[k * 64 + jt * 16 + nn]);
    }
}

// ---------- node-parallel pool ----------
__global__ void k_pool_par(const __hip_bfloat16* __restrict__ h,
                           const int* __restrict__ batch,
                           float* __restrict__ sums, int n) {
    int base = blockIdx.x * 128;
    int lim = base + 128; if (lim > n) lim = n;
    int j = threadIdx.x & 63, r = threadIdx.x >> 6;
    float acc = 0.0f; int gcur = -1;
    for (int i = base + r; i < lim; i += 4) {
        int g = batch[i];
        if (g != gcur) {
            if (gcur >= 0) atomicAdd(&sums[gcur * 64 + j], acc);
            acc = 0.0f; gcur = g;
        }
        acc += bf2f(h[(size_t)i * 64 + j]);
    }
    if (gcur >= 0) atomicAdd(&sums[gcur * 64 + j], acc);
}

// ---------- head ----------
__device__ inline int lower_bound_i(const int* __restrict__ a, int n, int key) {
    int lo = 0, hi = n;
    while (lo < hi) {
        int mid = (lo + hi) >> 1;
        if (a[mid] < key) lo = mid + 1; else hi = mid;
    }
    return lo;
}

__global__ void k_head(const float* __restrict__ sums, const int* __restrict__ batch,
                       const float* __restrict__ ge, const float* __restrict__ Wl,
                       const float* __restrict__ bl, float* __restrict__ out,
                       int n, int ng) {
    int g = blockIdx.x * blockDim.x + threadIdx.x;
    if (g < ng) {
        int lo = lower_bound_i(batch, n, g);
        int hi = lower_bound_i(batch, n, g + 1);
        float c = fmaxf((float)(hi - lo), 1.0f);
        float z[5];
        for (int cl = 0; cl < 5; cl++) z[cl] = bl[cl];
        for (int k = 0; k < 64; k++) {
            float p = sums[g * 64 + k] / c;
            for (int cl = 0; cl < 5; cl++) z[cl] += p * Wl[k * 5 + cl];
        }
        for (int k = 0; k < 64; k++) {
            float p = ge[g * 64 + k];
            for (int cl = 0; cl < 5; cl++) z[cl] += p * Wl[(64 + k) * 5 + cl];
        }
        float m = z[0];
        for (int cl = 1; cl < 5; cl++) m = fmaxf(m, z[cl]);
        float s = 0.0f;
        for (int cl = 0; cl < 5; cl++) s += expf(z[cl] - m);
        float lse = m + logf(s);
        for (int cl = 0; cl < 5; cl++) out[g * 5 + cl] = z[cl] - lse;
    }
}

#define ALIGN16(x) (((x) + 15) & ~(size_t)15)

extern "C" void kernel_launch(void* const* d_in, const int* in_sizes, int n_in,
                              void* d_out, int out_size, void* d_ws, size_t ws_size,
                              hipStream_t stream) {
    const float* x    = (const float*)d_in[0];
    const int*   ei   = (const int*)d_in[1];
    const int*   batch= (const int*)d_in[2];
    const float* ge   = (const float*)d_in[3];
    const float* W1   = (const float*)d_in[4];
    const float* b1   = (const float*)d_in[5];
    const float* W2   = (const float*)d_in[6];
    const float* b2   = (const float*)d_in[7];
    const float* W3   = (const float*)d_in[8];
    const float* b3   = (const float*)d_in[9];
    const float* Wl   = (const float*)d_in[10];
    const float* bl   = (const float*)d_in[11];
    float* out = (float*)d_out;

    const int N = in_sizes[0] / 2;   // x is [N,2]
    const int E = in_sizes[1] / 2;   // edge_index is [2,E]
    const int* src = ei;
    const int* dst = ei + E;
    const int NBUK = (N + 255) >> 8;             // actual dst buckets (<= NBIN)
    const int nbC  = (E + CHUNKB - 1) / CHUNKB;  // sort chunks

    // ---- workspace layout (segments 16B-aligned) ----
    char* wsb = (char*)d_ws;
    float* dinv   = (float*)wsb;                wsb += ALIGN16((size_t)N * 4);
    __hip_bfloat16* h16 = (__hip_bfloat16*)wsb;  wsb += ALIGN16((size_t)64 * N * 2);  // h1 / h3
    __hip_bfloat16* buf2= (__hip_bfloat16*)wsb;  wsb += ALIGN16((size_t)64 * N * 2);  // h2
    float* sums   = (float*)wsb;                wsb += ALIGN16((size_t)NG * 64 * 4);
    __hip_bfloat16* Wf2 = (__hip_bfloat16*)wsb; wsb += ALIGN16((size_t)4096 * 2);
    __hip_bfloat16* Wf3 = (__hip_bfloat16*)wsb; wsb += ALIGN16((size_t)4096 * 2);
    int2*  ebuck  = (int2*)wsb;                 wsb += ALIGN16((size_t)E * 8);
    int2*  csr    = (int2*)wsb;                 wsb += ALIGN16((size_t)E * 8);
    int*   row_ptr= (int*)wsb;                  wsb += ALIGN16((size_t)(N + 1) * 4);
    int*   hist   = (int*)wsb;                  wsb += ALIGN16((size_t)NBIN * nbC * 4);
    int*   bsums  = (int*)wsb;                  wsb += 512 * 4;

    const int BS = 256;
    int gN   = (N + BS - 1) / BS;
    int gF   = ((N + 15) / 16 + 3) / 4;          // k_aggLin: 4 waves * 16 nodes
    int gP   = (N + 127) / 128;                  // pool chunks
    int nH   = NBIN * nbC;
    int gH   = (nH + 511) / 512;                 // <= 512 for genscan2

    // ---- CSR build: single-pass bucket sort, all histograms in LDS ----
    hipMemsetAsync(sums, 0, (size_t)NG * 64 * 4, stream);
    k_bin_hist<<<nbC, BS, 0, stream>>>(dst, hist, E, nbC);
    genscan1<<<gH, 512, 0, stream>>>(hist, bsums, nH);
    genscan2<<<1, 512, 0, stream>>>(bsums, gH);
    k_bin_scatter<<<nbC, BS, 0, stream>>>(src, dst, hist, bsums, ebuck, E, nbC);
    k_csrA<<<NBUK, BS, 0, stream>>>(ebuck, hist, bsums, row_ptr, dinv, N, nbC, NBUK, E);
    k_csrB<<<NBUK, BS, 0, stream>>>(ebuck, hist, bsums, row_ptr, dinv, csr, nbC);
    k_prepW<<<2, 512, 0, stream>>>(W2, W3, Wf2, Wf3);

    // ---- layer 1: fused pull + lin1 + relu -> h1 (h16) ----
    k_layer1<<<gN, BS, 0, stream>>>(row_ptr, csr, x, dinv, W1, b1, h16, N);

    // ---- layer 2: fused agg(h1) + lin2 + relu -> h2 (buf2) ----
    k_aggLin<1><<<gF, BS, 0, stream>>>(row_ptr, csr, h16, dinv, Wf2, b2, buf2, N);

    // ---- layer 3: fused agg(h2) + lin3 -> h3 (h16) ----
    k_aggLin<0><<<gF, BS, 0, stream>>>(row_ptr, csr, buf2, dinv, Wf3, b3, h16, N);

    // ---- pool + head ----
    k_pool_par<<<gP, BS, 0, stream>>>(h16, batch, sums, N);
    k_head<<<1, 128, 0, stream>>>(sums, batch, ge, Wl, bl, out, N, NG);
}

// Round 13
// 231.972 us; speedup vs baseline: 5.2289x; 1.0590x over previous
//
#include <hip/hip_runtime.h>
#include <hip/hip_bf16.h>
#include <math.h>

#define NG 128
#define CHUNKB 4096
#define NBIN 512     // dst buckets of 256 nodes; >= ceil(N/256)
#define EWIN 320     // per-wave LDS edge window (16 nodes, avg deg 10 -> ~160)

typedef __attribute__((ext_vector_type(8))) short short8;
typedef __attribute__((ext_vector_type(4))) float float4v;

static __device__ __forceinline__ float bf2f(__hip_bfloat16 v) { return __bfloat162float(v); }

// ---------- per-chunk bucket histogram (LDS only, no global atomics) ----------
__global__ void k_bin_hist(const int* __restrict__ dst, int* __restrict__ hist,
                           int e, int nb) {
    __shared__ int h[NBIN];
    for (int i = threadIdx.x; i < NBIN; i += 256) h[i] = 0;
    __syncthreads();
    int base = blockIdx.x * CHUNKB;
    int lim = e - base; if (lim > CHUNKB) lim = CHUNKB;
    for (int k = threadIdx.x; k < lim; k += 256)
        atomicAdd(&h[dst[base + k] >> 8], 1);
    __syncthreads();
    for (int b = threadIdx.x; b < NBIN; b += 256) hist[b * nb + blockIdx.x] = h[b];
}

// ---------- generic exclusive scan (512-thread blocks) ----------
__global__ void __launch_bounds__(512) genscan1(int* __restrict__ a, int* __restrict__ bsums, int n) {
    __shared__ int s[512];
    int tid = threadIdx.x;
    int i = blockIdx.x * 512 + tid;
    int v = (i < n) ? a[i] : 0;
    s[tid] = v;
    __syncthreads();
    for (int d = 1; d < 512; d <<= 1) {
        int t = (tid >= d) ? s[tid - d] : 0;
        __syncthreads();
        s[tid] += t;
        __syncthreads();
    }
    if (i < n) a[i] = s[tid] - v;   // exclusive, in place
    if (tid == 511) bsums[blockIdx.x] = s[511];
}

__global__ void __launch_bounds__(512) genscan2(int* __restrict__ bsums, int nb) {
    __shared__ int s[512];
    int tid = threadIdx.x;
    int v = (tid < nb) ? bsums[tid] : 0;
    s[tid] = v;
    __syncthreads();
    for (int d = 1; d < 512; d <<= 1) {
        int t = (tid >= d) ? s[tid - d] : 0;
        __syncthreads();
        s[tid] += t;
        __syncthreads();
    }
    if (tid < nb) bsums[tid] = s[tid] - v;
}
// genscan3 fused into consumers: offset(i) = hist[i] + bsums[i >> 9]

// ---------- LDS-staged bucket scatter (exact offsets, clustered writes) ----------
__global__ void k_bin_scatter(const int* __restrict__ srcs, const int* __restrict__ dsts,
                              const int* __restrict__ offsets, const int* __restrict__ bsums,
                              int2* __restrict__ outbuf, int e, int nb) {
    __shared__ int hcnt[NBIN];     // counts -> cursor
    __shared__ int lstart[NBIN];   // local start -> delta
    __shared__ int ss[256];
    __shared__ int2 stage[CHUNKB];
    int tid = threadIdx.x, blk = blockIdx.x, base = blk * CHUNKB;
    int lim = e - base; if (lim > CHUNKB) lim = CHUNKB;
    for (int i = tid; i < NBIN; i += 256) hcnt[i] = 0;
    __syncthreads();
    for (int k = tid; k < lim; k += 256)
        atomicAdd(&hcnt[dsts[base + k] >> 8], 1);
    __syncthreads();
    int c0 = hcnt[2 * tid], c1 = hcnt[2 * tid + 1];
    int sum = c0 + c1;
    ss[tid] = sum;
    __syncthreads();
    for (int d = 1; d < 256; d <<= 1) {
        int t = (tid >= d) ? ss[tid - d] : 0;
        __syncthreads();
        ss[tid] += t;
        __syncthreads();
    }
    int excl = ss[tid] - sum;
    lstart[2 * tid] = excl;
    lstart[2 * tid + 1] = excl + c0;
    __syncthreads();
    hcnt[2 * tid] = excl;          // cursors
    hcnt[2 * tid + 1] = excl + c0;
    __syncthreads();
    for (int k = tid; k < lim; k += 256) {
        int2 ed = make_int2(srcs[base + k], dsts[base + k]);
        int p = atomicAdd(&hcnt[ed.y >> 8], 1);
        stage[p] = ed;
    }
    __syncthreads();
    for (int i = tid; i < NBIN; i += 256) {
        int gi = i * nb + blk;
        lstart[i] = offsets[gi] + bsums[gi >> 9] - lstart[i];
    }
    __syncthreads();
    for (int p = tid; p < lim; p += 256) {
        int2 ed = stage[p];
        outbuf[lstart[ed.y >> 8] + p] = ed;
    }
}

// ---------- block per bucket: per-node degree (LDS), row_ptr, dinv ----------
__global__ void k_csrA(const int2* __restrict__ ebuck, const int* __restrict__ offsets,
                       const int* __restrict__ bsums, int* __restrict__ row_ptr,
                       float* __restrict__ dinv, int n, int nb, int nbuk, int e_total) {
    __shared__ int lcnt[256];
    __shared__ int ssc[256];
    int b = blockIdx.x, tid = threadIdx.x, n0 = b << 8;
    lcnt[tid] = 0;
    __syncthreads();
    int i0 = b * nb, i1 = (b + 1) * nb;
    int e0 = offsets[i0] + bsums[i0 >> 9];
    int e1 = offsets[i1] + bsums[i1 >> 9];
    for (int i = e0 + tid; i < e1; i += 256)
        atomicAdd(&lcnt[ebuck[i].y - n0], 1);
    __syncthreads();
    int v = lcnt[tid];
    ssc[tid] = v;
    __syncthreads();
    for (int d = 1; d < 256; d <<= 1) {
        int t = (tid >= d) ? ssc[tid - d] : 0;
        __syncthreads();
        ssc[tid] += t;
        __syncthreads();
    }
    int node = n0 + tid;
    if (node < n) {
        row_ptr[node] = e0 + ssc[tid] - v;   // exclusive
        dinv[node] = rsqrtf((float)v + 1.0f);
        if (node == n - 1) row_ptr[n] = e_total;
    }
}

// ---------- block per bucket: place edges at exact CSR pos, precompute w ----------
__global__ void k_csrB(const int2* __restrict__ ebuck, const int* __restrict__ offsets,
                       const int* __restrict__ bsums, const int* __restrict__ row_ptr,
                       const float* __restrict__ dinv, int2* __restrict__ csr, int nb) {
    __shared__ int lcur[256];
    int b = blockIdx.x, tid = threadIdx.x, n0 = b << 8;
    lcur[tid] = 0;
    __syncthreads();
    int i0 = b * nb, i1 = (b + 1) * nb;
    int e0 = offsets[i0] + bsums[i0 >> 9];
    int e1 = offsets[i1] + bsums[i1 >> 9];
    for (int i = e0 + tid; i < e1; i += 256) {
        int2 ed = ebuck[i];
        int r = atomicAdd(&lcur[ed.y - n0], 1);
        int pos = row_ptr[ed.y] + r;
        float w = dinv[ed.x] * dinv[ed.y];
        csr[pos] = make_int2(ed.x, __float_as_int(w));
    }
}

// ---------- layer 1 fused: pull on x (2 feats) + lin1 + relu -> h1 bf16 ----------
__global__ void k_layer1(const int* __restrict__ row_ptr, const int2* __restrict__ edges,
                         const float* __restrict__ x, const float* __restrict__ dinv,
                         const float* __restrict__ W1, const float* __restrict__ b1,
                         __hip_bfloat16* __restrict__ h, int n) {
    __shared__ float w1s[128];
    __shared__ float b1s[64];
    if (threadIdx.x < 128) w1s[threadIdx.x] = W1[threadIdx.x];
    if (threadIdx.x < 64) b1s[threadIdx.x] = b1[threadIdx.x];
    __syncthreads();
    int i = blockIdx.x * blockDim.x + threadIdx.x;
    if (i >= n) return;
    const float2* x2 = (const float2*)x;
    float dd = dinv[i], d2 = dd * dd;
    float2 xi = x2[i];
    float a0 = d2 * xi.x, a1 = d2 * xi.y;
    int lo = row_ptr[i], hi = row_ptr[i + 1];
    int k = lo;
    for (; k + 4 <= hi; k += 4) {
        int2 e0 = edges[k], e1 = edges[k + 1], e2 = edges[k + 2], e3 = edges[k + 3];
        float2 v0 = x2[e0.x], v1 = x2[e1.x], v2 = x2[e2.x], v3 = x2[e3.x];
        a0 += __int_as_float(e0.y) * v0.x; a1 += __int_as_float(e0.y) * v0.y;
        a0 += __int_as_float(e1.y) * v1.x; a1 += __int_as_float(e1.y) * v1.y;
        a0 += __int_as_float(e2.y) * v2.x; a1 += __int_as_float(e2.y) * v2.y;
        a0 += __int_as_float(e3.y) * v3.x; a1 += __int_as_float(e3.y) * v3.y;
    }
    for (; k < hi; k++) {
        int2 e = edges[k];
        float2 v = x2[e.x];
        a0 += __int_as_float(e.y) * v.x;
        a1 += __int_as_float(e.y) * v.y;
    }
    short8* hv = reinterpret_cast<short8*>(h + (size_t)i * 64);
    #pragma unroll
    for (int g = 0; g < 8; g++) {
        short8 pack;
        #pragma unroll
        for (int j = 0; j < 8; j++) {
            int col = g * 8 + j;
            float v = fmaxf(a0 * w1s[col] + a1 * w1s[64 + col] + b1s[col], 0.0f);
            __hip_bfloat16 bv = __float2bfloat16(v);
            pack[j] = *reinterpret_cast<short*>(&bv);
        }
        hv[g] = pack;
    }
}

// ---------- per-node gather core (edges from LDS window or global) ----------
template <bool FAST>
static __device__ __forceinline__ void agg_node(int lo, int hi, int half, int col,
        const int2* __restrict__ gE, const int2* EW, int wave_lo,
        const uint* __restrict__ hinu, float& ax, float& ay) {
    for (int k = lo; k < hi; k += 16) {
        int ss[8]; float ww[8];
        #pragma unroll
        for (int j = 0; j < 8; j++) {
            int idx = k + 2 * j + half;
            int cidx = idx < hi ? idx : lo;      // clamped, always valid
            int2 ee = FAST ? EW[cidx - wave_lo] : gE[cidx];
            ss[j] = ee.x;
            ww[j] = idx < hi ? __int_as_float(ee.y) : 0.0f;
        }
        uint vv[8];
        #pragma unroll
        for (int j = 0; j < 8; j++) vv[j] = hinu[(size_t)ss[j] * 32 + col];
        #pragma unroll
        for (int j = 0; j < 8; j++) {
            ax += ww[j] * __int_as_float(vv[j] << 16);
            ay += ww[j] * __int_as_float(vv[j] & 0xffff0000u);
        }
    }
}

// ---------- fused agg + MFMA linear (+ optional fused mean-pool) ----------
// ONE wave per block (64 threads): wave-private LDS ~4.9 KB -> dense packing,
// many resident waves to hide the random h-gather latency.
template <int RELU, int POOL>
__global__ void __launch_bounds__(64, 6) k_aggLin(const int* __restrict__ row_ptr,
                                                  const int2* __restrict__ edges,
                                                  const __hip_bfloat16* __restrict__ hin,
                                                  const float* __restrict__ dinv,
                                                  const __hip_bfloat16* __restrict__ Wf,
                                                  const float* __restrict__ b,
                                                  __hip_bfloat16* __restrict__ hout,
                                                  const int* __restrict__ batch,
                                                  float* __restrict__ sums, int n) {
    __shared__ __attribute__((aligned(16))) __hip_bfloat16 T[16 * 72];
    __shared__ int2 EW[EWIN];
    int lane = threadIdx.x;
    int nb0 = blockIdx.x * 16;
    if (nb0 >= n) return;
    int half = lane >> 5, col = lane & 31;
    const uint* hinu = reinterpret_cast<const uint*>(hin);

    // lanes 0..16 hold the 17 row_ptr boundaries for this wave's nodes
    int bidx = nb0 + (lane < 16 ? lane : 16);
    if (bidx > n) bidx = n;
    int rp = row_ptr[bidx];
    int wave_lo = __shfl(rp, 0);
    int wave_hi = __shfl(rp, 16);
    int cnt = wave_hi - wave_lo;
    bool fast = (cnt <= EWIN);
    if (fast)
        for (int i = lane; i < cnt; i += 64) EW[i] = edges[wave_lo + i];
    // same-wave LDS write->read ordering (in-order LDS pipe; R10-R12 precedent)

    for (int nn = 0; nn < 16; nn++) {
        int node = nb0 + nn;
        float ax = 0.0f, ay = 0.0f;
        if (node < n) {
            if (half == 0) {               // self term counted once
                float dn = dinv[node];
                uint hv = hinu[(size_t)node * 32 + col];
                float dn2 = dn * dn;
                ax = dn2 * __int_as_float(hv << 16);
                ay = dn2 * __int_as_float(hv & 0xffff0000u);
            }
            int lo = __shfl(rp, nn), hi = __shfl(rp, nn + 1);
            if (fast) agg_node<true >(lo, hi, half, col, edges, EW, wave_lo, hinu, ax, ay);
            else      agg_node<false>(lo, hi, half, col, edges, EW, wave_lo, hinu, ax, ay);
        }
        ax += __shfl_xor(ax, 32);
        ay += __shfl_xor(ay, 32);
        if (half == 0) {
            __hip_bfloat16 bx = __float2bfloat16(ax);
            __hip_bfloat16 by = __float2bfloat16(ay);
            uint pack = (uint)(*reinterpret_cast<unsigned short*>(&bx)) |
                        ((uint)(*reinterpret_cast<unsigned short*>(&by)) << 16);
            *reinterpret_cast<uint*>(&T[nn * 72 + 2 * col]) = pack;
        }
    }

    // MFMA phase on the wave's 16x64 tile
    int m = lane & 15, q = lane >> 4;
    short8 a0 = *reinterpret_cast<const short8*>(&T[m * 72 + q * 8]);
    short8 a1 = *reinterpret_cast<const short8*>(&T[m * 72 + 32 + q * 8]);
    int lastn = nb0 + 15 < n ? nb0 + 15 : n - 1;
    bool onegraph = POOL && (nb0 + 15 < n) && (batch[nb0] == batch[lastn]);
    int gA = POOL ? batch[nb0] : 0;
    #pragma unroll
    for (int jt = 0; jt < 4; jt++) {
        short8 bf0 = *reinterpret_cast<const short8*>(Wf + ((size_t)(jt * 2 + 0) * 64 + lane) * 8);
        short8 bf1 = *reinterpret_cast<const short8*>(Wf + ((size_t)(jt * 2 + 1) * 64 + lane) * 8);
        float4v d = {0.0f, 0.0f, 0.0f, 0.0f};
        d = __builtin_amdgcn_mfma_f32_16x16x32_bf16(a0, bf0, d, 0, 0, 0);
        d = __builtin_amdgcn_mfma_f32_16x16x32_bf16(a1, bf1, d, 0, 0, 0);
        float bias = b[jt * 16 + m];           // C/D col = lane&15
        if (POOL) {
            if (onegraph) {
                float s = (d[0] + bias) + (d[1] + bias) + (d[2] + bias) + (d[3] + bias);
                s += __shfl_xor(s, 16);
                s += __shfl_xor(s, 32);
                if (q == 0) atomicAdd(&sums[gA * 64 + jt * 16 + m], s);
            } else {
                #pragma unroll
                for (int r = 0; r < 4; r++) {
                    int node = nb0 + q * 4 + r;
                    if (node < n)
                        atomicAdd(&sums[batch[node] * 64 + jt * 16 + m], d[r] + bias);
                }
            }
        } else {
            #pragma unroll
            for (int r = 0; r < 4; r++) {
                int node = nb0 + q * 4 + r;    // C/D row = quad*4 + reg
                if (node < n) {
                    float v = d[r] + bias;
                    if (RELU) v = fmaxf(v, 0.0f);
                    hout[(size_t)node * 64 + jt * 16 + m] = __float2bfloat16(v);
                }
            }
        }
    }
}

// ---------- pack W (64x64 fp32) into MFMA B-fragment order, bf16 ----------
__global__ void k_prepW(const float* __restrict__ W2, const float* __restrict__ W3,
                        __hip_bfloat16* __restrict__ Wf2, __hip_bfloat16* __restrict__ Wf3) {
    const float* W = blockIdx.x ? W3 : W2;
    __hip_bfloat16* Wf = blockIdx.x ? Wf3 : Wf2;
    int t = threadIdx.x;           // 0..511
    int c = t >> 6, l = t & 63;
    int jt = c >> 1, half = c & 1, nn = l & 15, q = l >> 4;
    #pragma unroll
    for (int j = 0; j < 8; j++) {
        int k = half * 32 + q * 8 + j;
        Wf[t * 8 + j] = __float2bfloat16(W[k * 64 + jt * 16 + nn]);
    }
}

// ---------- head (counts via binary search on sorted batch) ----------
__device__ inline int lower_bound_i(const int* __restrict__ a, int n, int key) {
    int lo = 0, hi = n;
    while (lo < hi) {
        int mid = (lo + hi) >> 1;
        if (a[mid] < key) lo = mid + 1; else hi = mid;
    }
    return lo;
}

__global__ void k_head(const float* __restrict__ sums, const int* __restrict__ batch,
                       const float* __restrict__ ge, const float* __restrict__ Wl,
                       const float* __restrict__ bl, float* __restrict__ out,
                       int n, int ng) {
    int g = blockIdx.x * blockDim.x + threadIdx.x;
    if (g < ng) {
        int lo = lower_bound_i(batch, n, g);
        int hi = lower_bound_i(batch, n, g + 1);
        float c = fmaxf((float)(hi - lo), 1.0f);
        float z[5];
        for (int cl = 0; cl < 5; cl++) z[cl] = bl[cl];
        for (int k = 0; k < 64; k++) {
            float p = sums[g * 64 + k] / c;
            for (int cl = 0; cl < 5; cl++) z[cl] += p * Wl[k * 5 + cl];
        }
        for (int k = 0; k < 64; k++) {
            float p = ge[g * 64 + k];
            for (int cl = 0; cl < 5; cl++) z[cl] += p * Wl[(64 + k) * 5 + cl];
        }
        float m = z[0];
        for (int cl = 1; cl < 5; cl++) m = fmaxf(m, z[cl]);
        float s = 0.0f;
        for (int cl = 0; cl < 5; cl++) s += expf(z[cl] - m);
        float lse = m + logf(s);
        for (int cl = 0; cl < 5; cl++) out[g * 5 + cl] = z[cl] - lse;
    }
}

#define ALIGN16(x) (((x) + 15) & ~(size_t)15)

extern "C" void kernel_launch(void* const* d_in, const int* in_sizes, int n_in,
                              void* d_out, int out_size, void* d_ws, size_t ws_size,
                              hipStream_t stream) {
    const float* x    = (const float*)d_in[0];
    const int*   ei   = (const int*)d_in[1];
    const int*   batch= (const int*)d_in[2];
    const float* ge   = (const float*)d_in[3];
    const float* W1   = (const float*)d_in[4];
    const float* b1   = (const float*)d_in[5];
    const float* W2   = (const float*)d_in[6];
    const float* b2   = (const float*)d_in[7];
    const float* W3   = (const float*)d_in[8];
    const float* b3   = (const float*)d_in[9];
    const float* Wl   = (const float*)d_in[10];
    const float* bl   = (const float*)d_in[11];
    float* out = (float*)d_out;

    const int N = in_sizes[0] / 2;   // x is [N,2]
    const int E = in_sizes[1] / 2;   // edge_index is [2,E]
    const int* src = ei;
    const int* dst = ei + E;
    const int NBUK = (N + 255) >> 8;             // actual dst buckets (<= NBIN)
    const int nbC  = (E + CHUNKB - 1) / CHUNKB;  // sort chunks

    // ---- workspace layout (segments 16B-aligned) ----
    char* wsb = (char*)d_ws;
    float* dinv   = (float*)wsb;                wsb += ALIGN16((size_t)N * 4);
    __hip_bfloat16* h16 = (__hip_bfloat16*)wsb;  wsb += ALIGN16((size_t)64 * N * 2);  // h1
    __hip_bfloat16* buf2= (__hip_bfloat16*)wsb;  wsb += ALIGN16((size_t)64 * N * 2);  // h2
    float* sums   = (float*)wsb;                wsb += ALIGN16((size_t)NG * 64 * 4);
    __hip_bfloat16* Wf2 = (__hip_bfloat16*)wsb; wsb += ALIGN16((size_t)4096 * 2);
    __hip_bfloat16* Wf3 = (__hip_bfloat16*)wsb; wsb += ALIGN16((size_t)4096 * 2);
    int2*  ebuck  = (int2*)wsb;                 wsb += ALIGN16((size_t)E * 8);
    int2*  csr    = (int2*)wsb;                 wsb += ALIGN16((size_t)E * 8);
    int*   row_ptr= (int*)wsb;                  wsb += ALIGN16((size_t)(N + 1) * 4);
    int*   hist   = (int*)wsb;                  wsb += ALIGN16((size_t)NBIN * nbC * 4);
    int*   bsums  = (int*)wsb;                  wsb += 512 * 4;

    const int BS = 256;
    int gN   = (N + BS - 1) / BS;
    int gF   = (N + 15) / 16;                    // k_aggLin: 1 wave (16 nodes) per block
    int nH   = NBIN * nbC;
    int gH   = (nH + 511) / 512;                 // <= 512 for genscan2

    // ---- CSR build: single-pass bucket sort, all histograms in LDS ----
    hipMemsetAsync(sums, 0, (size_t)NG * 64 * 4, stream);
    k_bin_hist<<<nbC, BS, 0, stream>>>(dst, hist, E, nbC);
    genscan1<<<gH, 512, 0, stream>>>(hist, bsums, nH);
    genscan2<<<1, 512, 0, stream>>>(bsums, gH);
    k_bin_scatter<<<nbC, BS, 0, stream>>>(src, dst, hist, bsums, ebuck, E, nbC);
    k_csrA<<<NBUK, BS, 0, stream>>>(ebuck, hist, bsums, row_ptr, dinv, N, nbC, NBUK, E);
    k_csrB<<<NBUK, BS, 0, stream>>>(ebuck, hist, bsums, row_ptr, dinv, csr, nbC);
    k_prepW<<<2, 512, 0, stream>>>(W2, W3, Wf2, Wf3);

    // ---- layer 1: fused pull + lin1 + relu -> h1 (h16) ----
    k_layer1<<<gN, BS, 0, stream>>>(row_ptr, csr, x, dinv, W1, b1, h16, N);

    // ---- layer 2: fused agg(h1) + lin2 + relu -> h2 (buf2) ----
    k_aggLin<1, 0><<<gF, 64, 0, stream>>>(row_ptr, csr, h16, dinv, Wf2, b2, buf2,
                                          nullptr, nullptr, N);

    // ---- layer 3: fused agg(h2) + lin3 + mean-pool -> sums (no h3 buffer) ----
    k_aggLin<0, 1><<<gF, 64, 0, stream>>>(row_ptr, csr, buf2, dinv, Wf3, b3, nullptr,
                                          batch, sums, N);

    // ---- head ----
    k_head<<<1, 128, 0, stream>>>(sums, batch, ge, Wl, bl, out, N, NG);
}

// Round 14
// 231.278 us; speedup vs baseline: 5.2446x; 1.0030x over previous
//
#include <hip/hip_runtime.h>
#include <hip/hip_bf16.h>
#include <math.h>

#define NG 128
#define CHUNKB 4096
#define NBIN 512     // dst buckets of 256 nodes; >= ceil(N/256)
#define EWIN 256     // per-wave LDS edge window (16 nodes, mean 160, 5-sigma ~225)

typedef __attribute__((ext_vector_type(8))) short short8;
typedef __attribute__((ext_vector_type(4))) float float4v;

static __device__ __forceinline__ float bf2f(__hip_bfloat16 v) { return __bfloat162float(v); }

// ---------- per-chunk bucket histogram (LDS only, no global atomics) ----------
__global__ void k_bin_hist(const int* __restrict__ dst, int* __restrict__ hist,
                           int e, int nb) {
    __shared__ int h[NBIN];
    for (int i = threadIdx.x; i < NBIN; i += 256) h[i] = 0;
    __syncthreads();
    int base = blockIdx.x * CHUNKB;
    int lim = e - base; if (lim > CHUNKB) lim = CHUNKB;
    for (int k = threadIdx.x; k < lim; k += 256)
        atomicAdd(&h[dst[base + k] >> 8], 1);
    __syncthreads();
    for (int b = threadIdx.x; b < NBIN; b += 256) hist[b * nb + blockIdx.x] = h[b];
}

// ---------- generic exclusive scan (512-thread blocks) ----------
__global__ void __launch_bounds__(512) genscan1(int* __restrict__ a, int* __restrict__ bsums, int n) {
    __shared__ int s[512];
    int tid = threadIdx.x;
    int i = blockIdx.x * 512 + tid;
    int v = (i < n) ? a[i] : 0;
    s[tid] = v;
    __syncthreads();
    for (int d = 1; d < 512; d <<= 1) {
        int t = (tid >= d) ? s[tid - d] : 0;
        __syncthreads();
        s[tid] += t;
        __syncthreads();
    }
    if (i < n) a[i] = s[tid] - v;   // exclusive, in place
    if (tid == 511) bsums[blockIdx.x] = s[511];
}

__global__ void __launch_bounds__(512) genscan2(int* __restrict__ bsums, int nb) {
    __shared__ int s[512];
    int tid = threadIdx.x;
    int v = (tid < nb) ? bsums[tid] : 0;
    s[tid] = v;
    __syncthreads();
    for (int d = 1; d < 512; d <<= 1) {
        int t = (tid >= d) ? s[tid - d] : 0;
        __syncthreads();
        s[tid] += t;
        __syncthreads();
    }
    if (tid < nb) bsums[tid] = s[tid] - v;
}
// genscan3 fused into consumers: offset(i) = hist[i] + bsums[i >> 9]

// ---------- LDS-staged bucket scatter (exact offsets, clustered writes) ----------
__global__ void k_bin_scatter(const int* __restrict__ srcs, const int* __restrict__ dsts,
                              const int* __restrict__ offsets, const int* __restrict__ bsums,
                              int2* __restrict__ outbuf, int e, int nb) {
    __shared__ int hcnt[NBIN];     // counts -> cursor
    __shared__ int lstart[NBIN];   // local start -> delta
    __shared__ int ss[256];
    __shared__ int2 stage[CHUNKB];
    int tid = threadIdx.x, blk = blockIdx.x, base = blk * CHUNKB;
    int lim = e - base; if (lim > CHUNKB) lim = CHUNKB;
    for (int i = tid; i < NBIN; i += 256) hcnt[i] = 0;
    __syncthreads();
    for (int k = tid; k < lim; k += 256)
        atomicAdd(&hcnt[dsts[base + k] >> 8], 1);
    __syncthreads();
    int c0 = hcnt[2 * tid], c1 = hcnt[2 * tid + 1];
    int sum = c0 + c1;
    ss[tid] = sum;
    __syncthreads();
    for (int d = 1; d < 256; d <<= 1) {
        int t = (tid >= d) ? ss[tid - d] : 0;
        __syncthreads();
        ss[tid] += t;
        __syncthreads();
    }
    int excl = ss[tid] - sum;
    lstart[2 * tid] = excl;
    lstart[2 * tid + 1] = excl + c0;
    __syncthreads();
    hcnt[2 * tid] = excl;          // cursors
    hcnt[2 * tid + 1] = excl + c0;
    __syncthreads();
    for (int k = tid; k < lim; k += 256) {
        int2 ed = make_int2(srcs[base + k], dsts[base + k]);
        int p = atomicAdd(&hcnt[ed.y >> 8], 1);
        stage[p] = ed;
    }
    __syncthreads();
    for (int i = tid; i < NBIN; i += 256) {
        int gi = i * nb + blk;
        lstart[i] = offsets[gi] + bsums[gi >> 9] - lstart[i];
    }
    __syncthreads();
    for (int p = tid; p < lim; p += 256) {
        int2 ed = stage[p];
        outbuf[lstart[ed.y >> 8] + p] = ed;
    }
}

// ---------- block per bucket: per-node degree (LDS), row_ptr, dinv ----------
__global__ void k_csrA(const int2* __restrict__ ebuck, const int* __restrict__ offsets,
                       const int* __restrict__ bsums, int* __restrict__ row_ptr,
                       float* __restrict__ dinv, int n, int nb, int nbuk, int e_total) {
    __shared__ int lcnt[256];
    __shared__ int ssc[256];
    int b = blockIdx.x, tid = threadIdx.x, n0 = b << 8;
    lcnt[tid] = 0;
    __syncthreads();
    int i0 = b * nb, i1 = (b + 1) * nb;
    int e0 = offsets[i0] + bsums[i0 >> 9];
    int e1 = offsets[i1] + bsums[i1 >> 9];
    for (int i = e0 + tid; i < e1; i += 256)
        atomicAdd(&lcnt[ebuck[i].y - n0], 1);
    __syncthreads();
    int v = lcnt[tid];
    ssc[tid] = v;
    __syncthreads();
    for (int d = 1; d < 256; d <<= 1) {
        int t = (tid >= d) ? ssc[tid - d] : 0;
        __syncthreads();
        ssc[tid] += t;
        __syncthreads();
    }
    int node = n0 + tid;
    if (node < n) {
        row_ptr[node] = e0 + ssc[tid] - v;   // exclusive
        dinv[node] = rsqrtf((float)v + 1.0f);
        if (node == n - 1) row_ptr[n] = e_total;
    }
}

// ---------- block per bucket: place edges at exact CSR pos, precompute w ----------
__global__ void k_csrB(const int2* __restrict__ ebuck, const int* __restrict__ offsets,
                       const int* __restrict__ bsums, const int* __restrict__ row_ptr,
                       const float* __restrict__ dinv, int2* __restrict__ csr, int nb) {
    __shared__ int lcur[256];
    int b = blockIdx.x, tid = threadIdx.x, n0 = b << 8;
    lcur[tid] = 0;
    __syncthreads();
    int i0 = b * nb, i1 = (b + 1) * nb;
    int e0 = offsets[i0] + bsums[i0 >> 9];
    int e1 = offsets[i1] + bsums[i1 >> 9];
    for (int i = e0 + tid; i < e1; i += 256) {
        int2 ed = ebuck[i];
        int r = atomicAdd(&lcur[ed.y - n0], 1);
        int pos = row_ptr[ed.y] + r;
        float w = dinv[ed.x] * dinv[ed.y];
        csr[pos] = make_int2(ed.x, __float_as_int(w));
    }
}

// ---------- layer 1 fused: pull on x (2 feats) + lin1 + relu -> h1 bf16 ----------
__global__ void k_layer1(const int* __restrict__ row_ptr, const int2* __restrict__ edges,
                         const float* __restrict__ x, const float* __restrict__ dinv,
                         const float* __restrict__ W1, const float* __restrict__ b1,
                         __hip_bfloat16* __restrict__ h, int n) {
    __shared__ float w1s[128];
    __shared__ float b1s[64];
    if (threadIdx.x < 128) w1s[threadIdx.x] = W1[threadIdx.x];
    if (threadIdx.x < 64) b1s[threadIdx.x] = b1[threadIdx.x];
    __syncthreads();
    int i = blockIdx.x * blockDim.x + threadIdx.x;
    if (i >= n) return;
    const float2* x2 = (const float2*)x;
    float dd = dinv[i], d2 = dd * dd;
    float2 xi = x2[i];
    float a0 = d2 * xi.x, a1 = d2 * xi.y;
    int lo = row_ptr[i], hi = row_ptr[i + 1];
    int k = lo;
    for (; k + 4 <= hi; k += 4) {
        int2 e0 = edges[k], e1 = edges[k + 1], e2 = edges[k + 2], e3 = edges[k + 3];
        float2 v0 = x2[e0.x], v1 = x2[e1.x], v2 = x2[e2.x], v3 = x2[e3.x];
        a0 += __int_as_float(e0.y) * v0.x; a1 += __int_as_float(e0.y) * v0.y;
        a0 += __int_as_float(e1.y) * v1.x; a1 += __int_as_float(e1.y) * v1.y;
        a0 += __int_as_float(e2.y) * v2.x; a1 += __int_as_float(e2.y) * v2.y;
        a0 += __int_as_float(e3.y) * v3.x; a1 += __int_as_float(e3.y) * v3.y;
    }
    for (; k < hi; k++) {
        int2 e = edges[k];
        float2 v = x2[e.x];
        a0 += __int_as_float(e.y) * v.x;
        a1 += __int_as_float(e.y) * v.y;
    }
    short8* hv = reinterpret_cast<short8*>(h + (size_t)i * 64);
    #pragma unroll
    for (int g = 0; g < 8; g++) {
        short8 pack;
        #pragma unroll
        for (int j = 0; j < 8; j++) {
            int col = g * 8 + j;
            float v = fmaxf(a0 * w1s[col] + a1 * w1s[64 + col] + b1s[col], 0.0f);
            __hip_bfloat16 bv = __float2bfloat16(v);
            pack[j] = *reinterpret_cast<short*>(&bv);
        }
        hv[g] = pack;
    }
}

// ---------- per-node gather core (edges from LDS window or global) ----------
template <bool FAST>
static __device__ __forceinline__ void agg_node(int lo, int hi, int half, int col,
        const int2* __restrict__ gE, const int2* EW, int wave_lo,
        const uint* __restrict__ hinu, float& ax, float& ay) {
    for (int k = lo; k < hi; k += 16) {
        int ss[8]; float ww[8];
        #pragma unroll
        for (int j = 0; j < 8; j++) {
            int idx = k + 2 * j + half;
            int cidx = idx < hi ? idx : lo;      // clamped, always valid
            int2 ee = FAST ? EW[cidx - wave_lo] : gE[cidx];
            ss[j] = ee.x;
            ww[j] = idx < hi ? __int_as_float(ee.y) : 0.0f;
        }
        uint vv[8];
        #pragma unroll
        for (int j = 0; j < 8; j++) vv[j] = hinu[(size_t)ss[j] * 32 + col];
        #pragma unroll
        for (int j = 0; j < 8; j++) {
            ax += ww[j] * __int_as_float(vv[j] << 16);
            ay += ww[j] * __int_as_float(vv[j] & 0xffff0000u);
        }
    }
}

// ---------- fused agg + MFMA linear (+ optional fused mean-pool) ----------
// ONE wave per block (64 threads), LDS 4.35 KB -> 32 blocks/CU; launch_bounds
// (64,8) caps VGPR at 64 for full 32-wave/CU residency to hide LLC gather latency.
template <int RELU, int POOL>
__global__ void __launch_bounds__(64, 8) k_aggLin(const int* __restrict__ row_ptr,
                                                  const int2* __restrict__ edges,
                                                  const __hip_bfloat16* __restrict__ hin,
                                                  const float* __restrict__ dinv,
                                                  const __hip_bfloat16* __restrict__ Wf,
                                                  const float* __restrict__ b,
                                                  __hip_bfloat16* __restrict__ hout,
                                                  const int* __restrict__ batch,
                                                  float* __restrict__ sums, int n) {
    __shared__ __attribute__((aligned(16))) __hip_bfloat16 T[16 * 72];
    __shared__ int2 EW[EWIN];
    int lane = threadIdx.x;
    int nb0 = blockIdx.x * 16;
    if (nb0 >= n) return;
    int half = lane >> 5, col = lane & 31;
    const uint* hinu = reinterpret_cast<const uint*>(hin);

    // lanes 0..16 hold the 17 row_ptr boundaries for this wave's nodes
    int bidx = nb0 + (lane < 16 ? lane : 16);
    if (bidx > n) bidx = n;
    int rp = row_ptr[bidx];
    int wave_lo = __shfl(rp, 0);
    int wave_hi = __shfl(rp, 16);
    int cnt = wave_hi - wave_lo;
    bool fast = (cnt <= EWIN);
    if (fast)
        for (int i = lane; i < cnt; i += 64) EW[i] = edges[wave_lo + i];
    // same-wave LDS write->read ordering (in-order LDS pipe; R10-R13 precedent)

    for (int nn = 0; nn < 16; nn++) {
        int node = nb0 + nn;
        float ax = 0.0f, ay = 0.0f;
        if (node < n) {
            if (half == 0) {               // self term counted once
                float dn = dinv[node];
                uint hv = hinu[(size_t)node * 32 + col];
                float dn2 = dn * dn;
                ax = dn2 * __int_as_float(hv << 16);
                ay = dn2 * __int_as_float(hv & 0xffff0000u);
            }
            int lo = __shfl(rp, nn), hi = __shfl(rp, nn + 1);
            if (fast) agg_node<true >(lo, hi, half, col, edges, EW, wave_lo, hinu, ax, ay);
            else      agg_node<false>(lo, hi, half, col, edges, EW, wave_lo, hinu, ax, ay);
        }
        ax += __shfl_xor(ax, 32);
        ay += __shfl_xor(ay, 32);
        if (half == 0) {
            __hip_bfloat16 bx = __float2bfloat16(ax);
            __hip_bfloat16 by = __float2bfloat16(ay);
            uint pack = (uint)(*reinterpret_cast<unsigned short*>(&bx)) |
                        ((uint)(*reinterpret_cast<unsigned short*>(&by)) << 16);
            *reinterpret_cast<uint*>(&T[nn * 72 + 2 * col]) = pack;
        }
    }

    // MFMA phase on the wave's 16x64 tile
    int m = lane & 15, q = lane >> 4;
    short8 a0 = *reinterpret_cast<const short8*>(&T[m * 72 + q * 8]);
    short8 a1 = *reinterpret_cast<const short8*>(&T[m * 72 + 32 + q * 8]);
    int lastn = nb0 + 15 < n ? nb0 + 15 : n - 1;
    bool onegraph = POOL && (nb0 + 15 < n) && (batch[nb0] == batch[lastn]);
    int gA = POOL ? batch[nb0] : 0;
    #pragma unroll
    for (int jt = 0; jt < 4; jt++) {
        short8 bf0 = *reinterpret_cast<const short8*>(Wf + ((size_t)(jt * 2 + 0) * 64 + lane) * 8);
        short8 bf1 = *reinterpret_cast<const short8*>(Wf + ((size_t)(jt * 2 + 1) * 64 + lane) * 8);
        float4v d = {0.0f, 0.0f, 0.0f, 0.0f};
        d = __builtin_amdgcn_mfma_f32_16x16x32_bf16(a0, bf0, d, 0, 0, 0);
        d = __builtin_amdgcn_mfma_f32_16x16x32_bf16(a1, bf1, d, 0, 0, 0);
        float bias = b[jt * 16 + m];           // C/D col = lane&15
        if (POOL) {
            if (onegraph) {
                float s = (d[0] + bias) + (d[1] + bias) + (d[2] + bias) + (d[3] + bias);
                s += __shfl_xor(s, 16);
                s += __shfl_xor(s, 32);
                if (q == 0) atomicAdd(&sums[gA * 64 + jt * 16 + m], s);
            } else {
                #pragma unroll
                for (int r = 0; r < 4; r++) {
                    int node = nb0 + q * 4 + r;
                    if (node < n)
                        atomicAdd(&sums[batch[node] * 64 + jt * 16 + m], d[r] + bias);
                }
            }
        } else {
            #pragma unroll
            for (int r = 0; r < 4; r++) {
                int node = nb0 + q * 4 + r;    // C/D row = quad*4 + reg
                if (node < n) {
                    float v = d[r] + bias;
                    if (RELU) v = fmaxf(v, 0.0f);
                    hout[(size_t)node * 64 + jt * 16 + m] = __float2bfloat16(v);
                }
            }
        }
    }
}

// ---------- pack W (64x64 fp32) into MFMA B-fragment order, bf16 ----------
__global__ void k_prepW(const float* __restrict__ W2, const float* __restrict__ W3,
                        __hip_bfloat16* __restrict__ Wf2, __hip_bfloat16* __restrict__ Wf3) {
    const float* W = blockIdx.x ? W3 : W2;
    __hip_bfloat16* Wf = blockIdx.x ? Wf3 : Wf2;
    int t = threadIdx.x;           // 0..511
    int c = t >> 6, l = t & 63;
    int jt = c >> 1, half = c & 1, nn = l & 15, q = l >> 4;
    #pragma unroll
    for (int j = 0; j < 8; j++) {
        int k = half * 32 + q * 8 + j;
        Wf[t * 8 + j] = __float2bfloat16(W[k * 64 + jt * 16 + nn]);
    }
}

// ---------- head (counts via binary search on sorted batch) ----------
__device__ inline int lower_bound_i(const int* __restrict__ a, int n, int key) {
    int lo = 0, hi = n;
    while (lo < hi) {
        int mid = (lo + hi) >> 1;
        if (a[mid] < key) lo = mid + 1; else hi = mid;
    }
    return lo;
}

__global__ void k_head(const float* __restrict__ sums, const int* __restrict__ batch,
                       const float* __restrict__ ge, const float* __restrict__ Wl,
                       const float* __restrict__ bl, float* __restrict__ out,
                       int n, int ng) {
    int g = blockIdx.x * blockDim.x + threadIdx.x;
    if (g < ng) {
        int lo = lower_bound_i(batch, n, g);
        int hi = lower_bound_i(batch, n, g + 1);
        float c = fmaxf((float)(hi - lo), 1.0f);
        float z[5];
        for (int cl = 0; cl < 5; cl++) z[cl] = bl[cl];
        for (int k = 0; k < 64; k++) {
            float p = sums[g * 64 + k] / c;
            for (int cl = 0; cl < 5; cl++) z[cl] += p * Wl[k * 5 + cl];
        }
        for (int k = 0; k < 64; k++) {
            float p = ge[g * 64 + k];
            for (int cl = 0; cl < 5; cl++) z[cl] += p * Wl[(64 + k) * 5 + cl];
        }
        float m = z[0];
        for (int cl = 1; cl < 5; cl++) m = fmaxf(m, z[cl]);
        float s = 0.0f;
        for (int cl = 0; cl < 5; cl++) s += expf(z[cl] - m);
        float lse = m + logf(s);
        for (int cl = 0; cl < 5; cl++) out[g * 5 + cl] = z[cl] - lse;
    }
}

#define ALIGN16(x) (((x) + 15) & ~(size_t)15)

extern "C" void kernel_launch(void* const* d_in, const int* in_sizes, int n_in,
                              void* d_out, int out_size, void* d_ws, size_t ws_size,
                              hipStream_t stream) {
    const float* x    = (const float*)d_in[0];
    const int*   ei   = (const int*)d_in[1];
    const int*   batch= (const int*)d_in[2];
    const float* ge   = (const float*)d_in[3];
    const float* W1   = (const float*)d_in[4];
    const float* b1   = (const float*)d_in[5];
    const float* W2   = (const float*)d_in[6];
    const float* b2   = (const float*)d_in[7];
    const float* W3   = (const float*)d_in[8];
    const float* b3   = (const float*)d_in[9];
    const float* Wl   = (const float*)d_in[10];
    const float* bl   = (const float*)d_in[11];
    float* out = (float*)d_out;

    const int N = in_sizes[0] / 2;   // x is [N,2]
    const int E = in_sizes[1] / 2;   // edge_index is [2,E]
    const int* src = ei;
    const int* dst = ei + E;
    const int NBUK = (N + 255) >> 8;             // actual dst buckets (<= NBIN)
    const int nbC  = (E + CHUNKB - 1) / CHUNKB;  // sort chunks

    // ---- workspace layout (segments 16B-aligned) ----
    char* wsb = (char*)d_ws;
    float* dinv   = (float*)wsb;                wsb += ALIGN16((size_t)N * 4);
    __hip_bfloat16* h16 = (__hip_bfloat16*)wsb;  wsb += ALIGN16((size_t)64 * N * 2);  // h1
    __hip_bfloat16* buf2= (__hip_bfloat16*)wsb;  wsb += ALIGN16((size_t)64 * N * 2);  // h2
    float* sums   = (float*)wsb;                wsb += ALIGN16((size_t)NG * 64 * 4);
    __hip_bfloat16* Wf2 = (__hip_bfloat16*)wsb; wsb += ALIGN16((size_t)4096 * 2);
    __hip_bfloat16* Wf3 = (__hip_bfloat16*)wsb; wsb += ALIGN16((size_t)4096 * 2);
    int2*  ebuck  = (int2*)wsb;                 wsb += ALIGN16((size_t)E * 8);
    int2*  csr    = (int2*)wsb;                 wsb += ALIGN16((size_t)E * 8);
    int*   row_ptr= (int*)wsb;                  wsb += ALIGN16((size_t)(N + 1) * 4);
    int*   hist   = (int*)wsb;                  wsb += ALIGN16((size_t)NBIN * nbC * 4);
    int*   bsums  = (int*)wsb;                  wsb += 512 * 4;

    const int BS = 256;
    int gN   = (N + BS - 1) / BS;
    int gF   = (N + 15) / 16;                    // k_aggLin: 1 wave (16 nodes) per block
    int nH   = NBIN * nbC;
    int gH   = (nH + 511) / 512;                 // <= 512 for genscan2

    // ---- CSR build: single-pass bucket sort, all histograms in LDS ----
    hipMemsetAsync(sums, 0, (size_t)NG * 64 * 4, stream);
    k_bin_hist<<<nbC, BS, 0, stream>>>(dst, hist, E, nbC);
    genscan1<<<gH, 512, 0, stream>>>(hist, bsums, nH);
    genscan2<<<1, 512, 0, stream>>>(bsums, gH);
    k_bin_scatter<<<nbC, BS, 0, stream>>>(src, dst, hist, bsums, ebuck, E, nbC);
    k_csrA<<<NBUK, BS, 0, stream>>>(ebuck, hist, bsums, row_ptr, dinv, N, nbC, NBUK, E);
    k_csrB<<<NBUK, BS, 0, stream>>>(ebuck, hist, bsums, row_ptr, dinv, csr, nbC);
    k_prepW<<<2, 512, 0, stream>>>(W2, W3, Wf2, Wf3);

    // ---- layer 1: fused pull + lin1 + relu -> h1 (h16) ----
    k_layer1<<<gN, BS, 0, stream>>>(row_ptr, csr, x, dinv, W1, b1, h16, N);

    // ---- layer 2: fused agg(h1) + lin2 + relu -> h2 (buf2) ----
    k_aggLin<1, 0><<<gF, 64, 0, stream>>>(row_ptr, csr, h16, dinv, Wf2, b2, buf2,
                                          nullptr, nullptr, N);

    // ---- layer 3: fused agg(h2) + lin3 + mean-pool -> sums (no h3 buffer) ----
    k_aggLin<0, 1><<<gF, 64, 0, stream>>>(row_ptr, csr, buf2, dinv, Wf3, b3, nullptr,
                                          batch, sums, N);

    // ---- head ----
    k_head<<<1, 128, 0, stream>>>(sums, batch, ge, Wl, bl, out, N, NG);
}